// Round 1
// baseline (1121.414 us; speedup 1.0000x reference)
//
#include <hip/hip_runtime.h>
#include <math.h>

// Problem constants (verified against reference): DIM=128, EMB=8, HID=128
// ws layout: Pa|Pb|H|M|agg|ssum|degf|expw|T2  (~130 MB)

// ---------------------------------------------------------------------------
// T2[t][j] = sum_u type_emb[t][u] * ew1[384+u][j] + eb1[j]   (folds eb1)
__global__ void prep_t2(const float* __restrict__ te, const float* __restrict__ ew1,
                        const float* __restrict__ eb1, float* __restrict__ T2) {
    int t = threadIdx.x;            // 256 threads
    int row = t >> 7, j = t & 127;
    float s = eb1[j];
#pragma unroll
    for (int u = 0; u < 8; ++u) s += te[row * 8 + u] * ew1[(384 + u) * 128 + j];
    T2[row * 128 + j] = s;
}

// ---------------------------------------------------------------------------
// Generic C[M,128] = act(A[M,128] @ B[128,128] + bias). fp32, tiled.
// Block: 256 thr (16x16), tile 64 rows x 128 cols, micro-tile 4x8, BK=32.
__global__ __launch_bounds__(256) void gemm128(const float* __restrict__ A,
                                               const float* __restrict__ B,
                                               const float* __restrict__ bias,
                                               float* __restrict__ C, int M, int relu) {
    __shared__ float As[64 * 132];   // +4 pad: bank-conflict-free a-reads
    __shared__ float Bs[32 * 132];
    const int t = threadIdx.x;
    const int tx = t & 15, ty = t >> 4;
    const int row0 = blockIdx.x * 64;

    // stage A tile 64x128 (guarded)
    {
        int r = t >> 2;
        int rr = row0 + r;
        const float* arow = A + (size_t)rr * 128;
#pragma unroll
        for (int j = 0; j < 8; ++j) {
            int c = ((t & 3) + 4 * j) * 4;
            float4 v = make_float4(0.f, 0.f, 0.f, 0.f);
            if (rr < M) v = *(const float4*)(arow + c);
            *(float4*)&As[r * 132 + c] = v;
        }
    }

    float acc[4][8];
#pragma unroll
    for (int i = 0; i < 4; ++i)
#pragma unroll
        for (int j = 0; j < 8; ++j) acc[i][j] = 0.f;

    for (int k0 = 0; k0 < 128; k0 += 32) {
        __syncthreads();   // As ready (iter0) / prev Bs readers done
        // stage Bs 32x128 (coalesced)
#pragma unroll
        for (int q = 0; q < 4; ++q) {
            int idx = t + 256 * q;           // float4 index 0..1023
            int kk = idx >> 5, c4 = idx & 31;
            float4 v = *(const float4*)(B + (size_t)(k0 + kk) * 128 + c4 * 4);
            *(float4*)&Bs[kk * 132 + c4 * 4] = v;
        }
        __syncthreads();
#pragma unroll 4
        for (int kk = 0; kk < 32; ++kk) {
            float a0 = As[(ty * 4 + 0) * 132 + k0 + kk];
            float a1 = As[(ty * 4 + 1) * 132 + k0 + kk];
            float a2 = As[(ty * 4 + 2) * 132 + k0 + kk];
            float a3 = As[(ty * 4 + 3) * 132 + k0 + kk];
            float4 b0 = *(float4*)&Bs[kk * 132 + tx * 8];
            float4 b1 = *(float4*)&Bs[kk * 132 + tx * 8 + 4];
            float bb[8] = {b0.x, b0.y, b0.z, b0.w, b1.x, b1.y, b1.z, b1.w};
#pragma unroll
            for (int j = 0; j < 8; ++j) {
                acc[0][j] = fmaf(a0, bb[j], acc[0][j]);
                acc[1][j] = fmaf(a1, bb[j], acc[1][j]);
                acc[2][j] = fmaf(a2, bb[j], acc[2][j]);
                acc[3][j] = fmaf(a3, bb[j], acc[3][j]);
            }
        }
    }

    // epilogue
    const int c0 = tx * 8;
    float bi[8] = {0, 0, 0, 0, 0, 0, 0, 0};
    if (bias) {
        float4 b0 = *(const float4*)(bias + c0);
        float4 b1 = *(const float4*)(bias + c0 + 4);
        bi[0] = b0.x; bi[1] = b0.y; bi[2] = b0.z; bi[3] = b0.w;
        bi[4] = b1.x; bi[5] = b1.y; bi[6] = b1.z; bi[7] = b1.w;
    }
#pragma unroll
    for (int i = 0; i < 4; ++i) {
        int rr = row0 + ty * 4 + i;
        if (rr >= M) continue;
        float o[8];
#pragma unroll
        for (int j = 0; j < 8; ++j) {
            o[j] = acc[i][j] + bi[j];
            if (relu) o[j] = fmaxf(o[j], 0.f);
        }
        float* crow = C + (size_t)rr * 128 + c0;
        *(float4*)crow = make_float4(o[0], o[1], o[2], o[3]);
        *(float4*)(crow + 4) = make_float4(o[4], o[5], o[6], o[7]);
    }
}

// ---------------------------------------------------------------------------
// Edge kernel: h = relu(|zi-zj|@Wc + Pa[src] + Pb[dst] + T2[et]);
// w = sigmoid(h.ew2 + eb2); expw[e]=exp(w); atomic ssum[src]+=exp(w), degf[src]+=1.
__global__ __launch_bounds__(256) void edge_mlp(
        const float* __restrict__ z, const int* __restrict__ ei,
        const int* __restrict__ etype, const float* __restrict__ Wc,
        const float* __restrict__ ew2, const float* __restrict__ eb2,
        const float* __restrict__ Pa, const float* __restrict__ Pb,
        const float* __restrict__ T2, float* __restrict__ expw,
        float* __restrict__ ssum, float* __restrict__ degf, int E) {
    __shared__ float Ds[64 * 132];
    __shared__ float Bs[32 * 132];
    __shared__ int srcs[64], dsts[64], ets[64];
    __shared__ float sEw2[128];
    const int t = threadIdx.x;
    const int tx = t & 15, ty = t >> 4;
    const int e0 = blockIdx.x * 64;   // E % 64 == 0

    if (t < 64)        srcs[t] = ei[e0 + t];
    else if (t < 128)  dsts[t - 64] = ei[E + e0 + (t - 64)];
    else if (t < 192)  ets[t - 128] = etype[e0 + (t - 128)];
    else { int i = t - 192; sEw2[i] = ew2[i]; sEw2[i + 64] = ew2[i + 64]; }
    __syncthreads();

    // build D = |zi - zj| tile, 64 x 128
    {
        int r = t >> 2;
        const float* zi = z + (size_t)srcs[r] * 128;
        const float* zj = z + (size_t)dsts[r] * 128;
#pragma unroll
        for (int j = 0; j < 8; ++j) {
            int c = ((t & 3) + 4 * j) * 4;
            float4 a = *(const float4*)(zi + c);
            float4 b = *(const float4*)(zj + c);
            float4 v = make_float4(fabsf(a.x - b.x), fabsf(a.y - b.y),
                                   fabsf(a.z - b.z), fabsf(a.w - b.w));
            *(float4*)&Ds[r * 132 + c] = v;
        }
    }

    float acc[4][8];
#pragma unroll
    for (int i = 0; i < 4; ++i)
#pragma unroll
        for (int j = 0; j < 8; ++j) acc[i][j] = 0.f;

    for (int k0 = 0; k0 < 128; k0 += 32) {
        __syncthreads();
#pragma unroll
        for (int q = 0; q < 4; ++q) {
            int idx = t + 256 * q;
            int kk = idx >> 5, c4 = idx & 31;
            float4 v = *(const float4*)(Wc + (size_t)(k0 + kk) * 128 + c4 * 4);
            *(float4*)&Bs[kk * 132 + c4 * 4] = v;
        }
        __syncthreads();
#pragma unroll 4
        for (int kk = 0; kk < 32; ++kk) {
            float a0 = Ds[(ty * 4 + 0) * 132 + k0 + kk];
            float a1 = Ds[(ty * 4 + 1) * 132 + k0 + kk];
            float a2 = Ds[(ty * 4 + 2) * 132 + k0 + kk];
            float a3 = Ds[(ty * 4 + 3) * 132 + k0 + kk];
            float4 b0 = *(float4*)&Bs[kk * 132 + tx * 8];
            float4 b1 = *(float4*)&Bs[kk * 132 + tx * 8 + 4];
            float bb[8] = {b0.x, b0.y, b0.z, b0.w, b1.x, b1.y, b1.z, b1.w};
#pragma unroll
            for (int j = 0; j < 8; ++j) {
                acc[0][j] = fmaf(a0, bb[j], acc[0][j]);
                acc[1][j] = fmaf(a1, bb[j], acc[1][j]);
                acc[2][j] = fmaf(a2, bb[j], acc[2][j]);
                acc[3][j] = fmaf(a3, bb[j], acc[3][j]);
            }
        }
    }

    // epilogue: add node terms, relu, second layer dot, sigmoid/exp, atomics
    const int c0 = tx * 8;
    float w2v[8];
    {
        float4 w0 = *(float4*)&sEw2[c0];
        float4 w1 = *(float4*)&sEw2[c0 + 4];
        w2v[0] = w0.x; w2v[1] = w0.y; w2v[2] = w0.z; w2v[3] = w0.w;
        w2v[4] = w1.x; w2v[5] = w1.y; w2v[6] = w1.z; w2v[7] = w1.w;
    }
    const float eb2v = eb2[0];
#pragma unroll
    for (int i = 0; i < 4; ++i) {
        int r = ty * 4 + i;
        int e = e0 + r;
        int sn = srcs[r], dn = dsts[r], tt = ets[r];
        const float* pa = Pa + (size_t)sn * 128 + c0;
        const float* pb = Pb + (size_t)dn * 128 + c0;
        const float* t2 = T2 + tt * 128 + c0;
        float4 pa0 = *(const float4*)pa, pa1 = *(const float4*)(pa + 4);
        float4 pb0 = *(const float4*)pb, pb1 = *(const float4*)(pb + 4);
        float4 t20 = *(const float4*)t2, t21 = *(const float4*)(t2 + 4);
        float ad[8] = {pa0.x + pb0.x + t20.x, pa0.y + pb0.y + t20.y,
                       pa0.z + pb0.z + t20.z, pa0.w + pb0.w + t20.w,
                       pa1.x + pb1.x + t21.x, pa1.y + pb1.y + t21.y,
                       pa1.z + pb1.z + t21.z, pa1.w + pb1.w + t21.w};
        float partial = 0.f;
#pragma unroll
        for (int j = 0; j < 8; ++j) {
            float h = fmaxf(acc[i][j] + ad[j], 0.f);
            partial = fmaf(h, w2v[j], partial);
        }
        // reduce over tx (lanes 0..15 within wave quarter)
        partial += __shfl_xor(partial, 1);
        partial += __shfl_xor(partial, 2);
        partial += __shfl_xor(partial, 4);
        partial += __shfl_xor(partial, 8);
        if (tx == 0) {
            float logit = partial + eb2v;
            float w = 1.f / (1.f + expf(-logit));
            float ew = expf(w);
            expw[e] = ew;
            atomicAdd(&ssum[sn], ew);
            atomicAdd(&degf[sn], 1.f);
        }
    }
}

// ---------------------------------------------------------------------------
// agg[src[e]] += M[dst[e]]  (one thread per edge x 4-col chunk)
__global__ void scatter_msum(const float* __restrict__ Mx, const int* __restrict__ ei,
                             float* __restrict__ agg, int E) {
    int tid = blockIdx.x * 256 + threadIdx.x;
    int e = tid >> 5, c4 = tid & 31;
    if (e >= E) return;
    int sn = ei[e];
    int dn = ei[E + e];
    float4 v = *(const float4*)(Mx + (size_t)dn * 128 + c4 * 4);
    float* d = agg + (size_t)sn * 128 + c4 * 4;
    atomicAdd(d + 0, v.x);
    atomicAdd(d + 1, v.y);
    atomicAdd(d + 2, v.z);
    atomicAdd(d + 3, v.w);
}

// ---------------------------------------------------------------------------
__global__ void alpha_k(const float* __restrict__ expw, const int* __restrict__ ei,
                        const float* __restrict__ ssum, float* __restrict__ oa, int E) {
    int e = blockIdx.x * 256 + threadIdx.x;
    if (e >= E) return;
    oa[e] = expw[e] / (ssum[ei[e]] + 1e-12f);
}

// ---------------------------------------------------------------------------
// x = z + agg/(deg+1e-12); LayerNorm(x) * gamma + beta. One wave per node.
__global__ __launch_bounds__(256) void ln_k(const float* __restrict__ z,
                                            const float* __restrict__ agg,
                                            const float* __restrict__ degf,
                                            const float* __restrict__ gamma,
                                            const float* __restrict__ beta,
                                            float* __restrict__ out, int N) {
    int wid = threadIdx.x >> 6, lane = threadIdx.x & 63;
    int n = blockIdx.x * 4 + wid;
    if (n >= N) return;
    float inv = 1.f / (degf[n] + 1e-12f);
    size_t base = (size_t)n * 128;
    float x0 = z[base + lane] + agg[base + lane] * inv;
    float x1 = z[base + lane + 64] + agg[base + lane + 64] * inv;
    float s = x0 + x1;
#pragma unroll
    for (int off = 1; off < 64; off <<= 1) s += __shfl_xor(s, off);
    float mu = s * (1.f / 128.f);
    float d0 = x0 - mu, d1 = x1 - mu;
    float v = d0 * d0 + d1 * d1;
#pragma unroll
    for (int off = 1; off < 64; off <<= 1) v += __shfl_xor(v, off);
    float rs = rsqrtf(v * (1.f / 128.f) + 1e-5f);
    out[base + lane] = d0 * rs * gamma[lane] + beta[lane];
    out[base + lane + 64] = d1 * rs * gamma[lane + 64] + beta[lane + 64];
}

// ---------------------------------------------------------------------------
extern "C" void kernel_launch(void* const* d_in, const int* in_sizes, int n_in,
                              void* d_out, int out_size, void* d_ws, size_t ws_size,
                              hipStream_t stream) {
    const float* z     = (const float*)d_in[0];
    const int*   ei    = (const int*)d_in[1];
    const int*   et    = (const int*)d_in[2];
    const float* temb  = (const float*)d_in[3];
    const float* ew1   = (const float*)d_in[4];
    const float* eb1   = (const float*)d_in[5];
    const float* ew2   = (const float*)d_in[6];
    const float* eb2   = (const float*)d_in[7];
    const float* mw1   = (const float*)d_in[8];
    const float* mb1   = (const float*)d_in[9];
    const float* mw2   = (const float*)d_in[10];
    const float* mb2   = (const float*)d_in[11];
    const float* gamma = (const float*)d_in[12];
    const float* beta  = (const float*)d_in[13];

    const int N = in_sizes[0] / 128;
    const int E = in_sizes[2];

    char* ws = (char*)d_ws;
    size_t off = 0;
    auto take = [&](size_t b) { char* p = ws + off; off += (b + 255) & ~(size_t)255; return p; };
    float* Pa   = (float*)take((size_t)N * 128 * 4);
    float* Pb   = (float*)take((size_t)N * 128 * 4);
    float* H    = (float*)take((size_t)N * 128 * 4);
    float* Mx   = (float*)take((size_t)N * 128 * 4);
    char*  z0   = ws + off;                       // contiguous zero region
    float* agg  = (float*)take((size_t)N * 128 * 4);
    float* ssum = (float*)take((size_t)N * 4);
    float* degf = (float*)take((size_t)N * 4);
    size_t zb   = (size_t)((ws + off) - z0);
    float* expw = (float*)take((size_t)E * 4);
    float* T2   = (float*)take(2 * 128 * 4);

    float* out_x = (float*)d_out;
    float* out_a = out_x + (size_t)N * 128;

    hipMemsetAsync(z0, 0, zb, stream);
    prep_t2<<<1, 256, 0, stream>>>(temb, ew1, eb1, T2);

    int gb = (N + 63) / 64;
    gemm128<<<gb, 256, 0, stream>>>(z, ew1, nullptr, Pa, N, 0);            // Pa = z @ Wa
    gemm128<<<gb, 256, 0, stream>>>(z, ew1 + 128 * 128, nullptr, Pb, N, 0); // Pb = z @ Wb
    gemm128<<<gb, 256, 0, stream>>>(z, mw1, mb1, H, N, 1);                  // H = relu(z@mw1+mb1)
    gemm128<<<gb, 256, 0, stream>>>(H, mw2, mb2, Mx, N, 0);                 // M = H@mw2+mb2

    edge_mlp<<<(E + 63) / 64, 256, 0, stream>>>(z, ei, et, ew1 + 256 * 128,
                                                ew2, eb2, Pa, Pb, T2, expw, ssum, degf, E);
    scatter_msum<<<(E * 32 + 255) / 256, 256, 0, stream>>>(Mx, ei, agg, E);
    alpha_k<<<(E + 255) / 256, 256, 0, stream>>>(expw, ei, ssum, out_a, E);
    ln_k<<<(N + 3) / 4, 256, 0, stream>>>(z, agg, degf, gamma, beta, out_x, N);
}

// Round 5
// 554.904 us; speedup vs baseline: 2.0209x; 2.0209x over previous
//
#include <hip/hip_runtime.h>
#include <math.h>

// DIM=128, EMB=8, HID=128, N=50000, E=400000
// Strategy: node-level factorization of the edge MLP + CSR gather (no float atomics).
// ws layout: Pa|Pb|H|Mx|ssum|deg|cursor|rowstart|cdst|expw|T2

// ---------------------------------------------------------------------------
// T2[t][j] = sum_u type_emb[t][u] * ew1[384+u][j] + eb1[j]   (folds eb1)
__global__ void prep_t2(const float* __restrict__ te, const float* __restrict__ ew1,
                        const float* __restrict__ eb1, float* __restrict__ T2) {
    int t = threadIdx.x;            // 256 threads
    int row = t >> 7, j = t & 127;
    float s = eb1[j];
#pragma unroll
    for (int u = 0; u < 8; ++u) s += te[row * 8 + u] * ew1[(384 + u) * 128 + j];
    T2[row * 128 + j] = s;
}

// ---------------------------------------------------------------------------
// deg[src[e]]++ histogram
__global__ void deg_count(const int* __restrict__ ei, int* __restrict__ deg, int E) {
    int e = blockIdx.x * 256 + threadIdx.x;
    if (e >= E) return;
    atomicAdd(&deg[ei[e]], 1);
}

// ---------------------------------------------------------------------------
// Single-block exclusive scan of deg[0..N) -> rowstart[0..N). 1024 threads.
__global__ __launch_bounds__(1024) void scan_deg(const int* __restrict__ deg,
                                                 int* __restrict__ rowstart, int N) {
    __shared__ int wsum[16];
    __shared__ int carry_s;
    const int lane = threadIdx.x & 63, wid = threadIdx.x >> 6;
    if (threadIdx.x == 0) carry_s = 0;
    __syncthreads();
    for (int base = 0; base < N; base += 1024) {
        int i = base + threadIdx.x;
        int v = (i < N) ? deg[i] : 0;
        int x = v;
#pragma unroll
        for (int off = 1; off < 64; off <<= 1) {
            int t = __shfl_up(x, off);
            if (lane >= off) x += t;
        }
        if (lane == 63) wsum[wid] = x;
        __syncthreads();
        if (wid == 0 && lane < 16) {
            int s = wsum[lane];
#pragma unroll
            for (int off = 1; off < 16; off <<= 1) {
                int t = __shfl_up(s, off);
                if (lane >= off) s += t;
            }
            wsum[lane] = s;
        }
        __syncthreads();
        int wexcl = (wid == 0) ? 0 : wsum[wid - 1];
        int carry = carry_s;
        if (i < N) rowstart[i] = carry + wexcl + x - v;
        __syncthreads();
        if (threadIdx.x == 0) carry_s = carry + wsum[15];
        __syncthreads();
    }
}

// ---------------------------------------------------------------------------
// cdst[rowstart[src]+k] = dst  (k via per-node cursor)
__global__ void place_edges(const int* __restrict__ ei, int* __restrict__ cursor,
                            const int* __restrict__ rowstart, int* __restrict__ cdst, int E) {
    int e = blockIdx.x * 256 + threadIdx.x;
    if (e >= E) return;
    int s = ei[e], d = ei[E + e];
    int slot = rowstart[s] + atomicAdd(&cursor[s], 1);
    cdst[slot] = d;
}

// ---------------------------------------------------------------------------
// Generic C[M,128] = act(A[M,128] @ B[128,128] + bias). fp32, tiled.
__global__ __launch_bounds__(256) void gemm128(const float* __restrict__ A,
                                               const float* __restrict__ B,
                                               const float* __restrict__ bias,
                                               float* __restrict__ C, int M, int relu) {
    __shared__ float As[64 * 132];
    __shared__ float Bs[32 * 132];
    const int t = threadIdx.x;
    const int tx = t & 15, ty = t >> 4;
    const int row0 = blockIdx.x * 64;

    {
        int r = t >> 2;
        int rr = row0 + r;
        const float* arow = A + (size_t)rr * 128;
#pragma unroll
        for (int j = 0; j < 8; ++j) {
            int c = ((t & 3) + 4 * j) * 4;
            float4 v = make_float4(0.f, 0.f, 0.f, 0.f);
            if (rr < M) v = *(const float4*)(arow + c);
            *(float4*)&As[r * 132 + c] = v;
        }
    }

    float acc[4][8];
#pragma unroll
    for (int i = 0; i < 4; ++i)
#pragma unroll
        for (int j = 0; j < 8; ++j) acc[i][j] = 0.f;

    for (int k0 = 0; k0 < 128; k0 += 32) {
        __syncthreads();
#pragma unroll
        for (int q = 0; q < 4; ++q) {
            int idx = t + 256 * q;
            int kk = idx >> 5, c4 = idx & 31;
            float4 v = *(const float4*)(B + (size_t)(k0 + kk) * 128 + c4 * 4);
            *(float4*)&Bs[kk * 132 + c4 * 4] = v;
        }
        __syncthreads();
#pragma unroll 4
        for (int kk = 0; kk < 32; ++kk) {
            float a0 = As[(ty * 4 + 0) * 132 + k0 + kk];
            float a1 = As[(ty * 4 + 1) * 132 + k0 + kk];
            float a2 = As[(ty * 4 + 2) * 132 + k0 + kk];
            float a3 = As[(ty * 4 + 3) * 132 + k0 + kk];
            float4 b0 = *(float4*)&Bs[kk * 132 + tx * 8];
            float4 b1 = *(float4*)&Bs[kk * 132 + tx * 8 + 4];
            float bb[8] = {b0.x, b0.y, b0.z, b0.w, b1.x, b1.y, b1.z, b1.w};
#pragma unroll
            for (int j = 0; j < 8; ++j) {
                acc[0][j] = fmaf(a0, bb[j], acc[0][j]);
                acc[1][j] = fmaf(a1, bb[j], acc[1][j]);
                acc[2][j] = fmaf(a2, bb[j], acc[2][j]);
                acc[3][j] = fmaf(a3, bb[j], acc[3][j]);
            }
        }
    }

    const int c0 = tx * 8;
    float bi[8] = {0, 0, 0, 0, 0, 0, 0, 0};
    if (bias) {
        float4 b0 = *(const float4*)(bias + c0);
        float4 b1 = *(const float4*)(bias + c0 + 4);
        bi[0] = b0.x; bi[1] = b0.y; bi[2] = b0.z; bi[3] = b0.w;
        bi[4] = b1.x; bi[5] = b1.y; bi[6] = b1.z; bi[7] = b1.w;
    }
#pragma unroll
    for (int i = 0; i < 4; ++i) {
        int rr = row0 + ty * 4 + i;
        if (rr >= M) continue;
        float o[8];
#pragma unroll
        for (int j = 0; j < 8; ++j) {
            o[j] = acc[i][j] + bi[j];
            if (relu) o[j] = fmaxf(o[j], 0.f);
        }
        float* crow = C + (size_t)rr * 128 + c0;
        *(float4*)crow = make_float4(o[0], o[1], o[2], o[3]);
        *(float4*)(crow + 4) = make_float4(o[4], o[5], o[6], o[7]);
    }
}

// ---------------------------------------------------------------------------
// Edge kernel: h = relu(|zi-zj|@Wc + Pa[src] + Pb[dst] + T2[et]);
// w = sigmoid(h.ew2 + eb2); expw[e]=exp(w); atomic ssum[src]+=exp(w).
__global__ __launch_bounds__(256) void edge_mlp(
        const float* __restrict__ z, const int* __restrict__ ei,
        const int* __restrict__ etype, const float* __restrict__ Wc,
        const float* __restrict__ ew2, const float* __restrict__ eb2,
        const float* __restrict__ Pa, const float* __restrict__ Pb,
        const float* __restrict__ T2, float* __restrict__ expw,
        float* __restrict__ ssum, int E) {
    __shared__ float Ds[64 * 132];
    __shared__ float Bs[32 * 132];
    __shared__ int srcs[64], dsts[64], ets[64];
    __shared__ float sEw2[128];
    const int t = threadIdx.x;
    const int tx = t & 15, ty = t >> 4;
    const int e0 = blockIdx.x * 64;   // E % 64 == 0

    if (t < 64)        srcs[t] = ei[e0 + t];
    else if (t < 128)  dsts[t - 64] = ei[E + e0 + (t - 64)];
    else if (t < 192)  ets[t - 128] = etype[e0 + (t - 128)];
    else { int i = t - 192; sEw2[i] = ew2[i]; sEw2[i + 64] = ew2[i + 64]; }
    __syncthreads();

    {
        int r = t >> 2;
        const float* zi = z + (size_t)srcs[r] * 128;
        const float* zj = z + (size_t)dsts[r] * 128;
#pragma unroll
        for (int j = 0; j < 8; ++j) {
            int c = ((t & 3) + 4 * j) * 4;
            float4 a = *(const float4*)(zi + c);
            float4 b = *(const float4*)(zj + c);
            float4 v = make_float4(fabsf(a.x - b.x), fabsf(a.y - b.y),
                                   fabsf(a.z - b.z), fabsf(a.w - b.w));
            *(float4*)&Ds[r * 132 + c] = v;
        }
    }

    float acc[4][8];
#pragma unroll
    for (int i = 0; i < 4; ++i)
#pragma unroll
        for (int j = 0; j < 8; ++j) acc[i][j] = 0.f;

    for (int k0 = 0; k0 < 128; k0 += 32) {
        __syncthreads();
#pragma unroll
        for (int q = 0; q < 4; ++q) {
            int idx = t + 256 * q;
            int kk = idx >> 5, c4 = idx & 31;
            float4 v = *(const float4*)(Wc + (size_t)(k0 + kk) * 128 + c4 * 4);
            *(float4*)&Bs[kk * 132 + c4 * 4] = v;
        }
        __syncthreads();
#pragma unroll 4
        for (int kk = 0; kk < 32; ++kk) {
            float a0 = Ds[(ty * 4 + 0) * 132 + k0 + kk];
            float a1 = Ds[(ty * 4 + 1) * 132 + k0 + kk];
            float a2 = Ds[(ty * 4 + 2) * 132 + k0 + kk];
            float a3 = Ds[(ty * 4 + 3) * 132 + k0 + kk];
            float4 b0 = *(float4*)&Bs[kk * 132 + tx * 8];
            float4 b1 = *(float4*)&Bs[kk * 132 + tx * 8 + 4];
            float bb[8] = {b0.x, b0.y, b0.z, b0.w, b1.x, b1.y, b1.z, b1.w};
#pragma unroll
            for (int j = 0; j < 8; ++j) {
                acc[0][j] = fmaf(a0, bb[j], acc[0][j]);
                acc[1][j] = fmaf(a1, bb[j], acc[1][j]);
                acc[2][j] = fmaf(a2, bb[j], acc[2][j]);
                acc[3][j] = fmaf(a3, bb[j], acc[3][j]);
            }
        }
    }

    const int c0 = tx * 8;
    float w2v[8];
    {
        float4 w0 = *(float4*)&sEw2[c0];
        float4 w1 = *(float4*)&sEw2[c0 + 4];
        w2v[0] = w0.x; w2v[1] = w0.y; w2v[2] = w0.z; w2v[3] = w0.w;
        w2v[4] = w1.x; w2v[5] = w1.y; w2v[6] = w1.z; w2v[7] = w1.w;
    }
    const float eb2v = eb2[0];
#pragma unroll
    for (int i = 0; i < 4; ++i) {
        int r = ty * 4 + i;
        int e = e0 + r;
        int sn = srcs[r], dn = dsts[r], tt = ets[r];
        const float* pa = Pa + (size_t)sn * 128 + c0;
        const float* pb = Pb + (size_t)dn * 128 + c0;
        const float* t2 = T2 + tt * 128 + c0;
        float4 pa0 = *(const float4*)pa, pa1 = *(const float4*)(pa + 4);
        float4 pb0 = *(const float4*)pb, pb1 = *(const float4*)(pb + 4);
        float4 t20 = *(const float4*)t2, t21 = *(const float4*)(t2 + 4);
        float ad[8] = {pa0.x + pb0.x + t20.x, pa0.y + pb0.y + t20.y,
                       pa0.z + pb0.z + t20.z, pa0.w + pb0.w + t20.w,
                       pa1.x + pb1.x + t21.x, pa1.y + pb1.y + t21.y,
                       pa1.z + pb1.z + t21.z, pa1.w + pb1.w + t21.w};
        float partial = 0.f;
#pragma unroll
        for (int j = 0; j < 8; ++j) {
            float h = fmaxf(acc[i][j] + ad[j], 0.f);
            partial = fmaf(h, w2v[j], partial);
        }
        partial += __shfl_xor(partial, 1);
        partial += __shfl_xor(partial, 2);
        partial += __shfl_xor(partial, 4);
        partial += __shfl_xor(partial, 8);
        if (tx == 0) {
            float logit = partial + eb2v;
            float w = 1.f / (1.f + expf(-logit));
            float ew = expf(w);
            expw[e] = ew;
            atomicAdd(&ssum[sn], ew);
        }
    }
}

// ---------------------------------------------------------------------------
__global__ void alpha_k(const float* __restrict__ expw, const int* __restrict__ ei,
                        const float* __restrict__ ssum, float* __restrict__ oa, int E) {
    int e = blockIdx.x * 256 + threadIdx.x;
    if (e >= E) return;
    oa[e] = expw[e] / (ssum[ei[e]] + 1e-12f);
}

// ---------------------------------------------------------------------------
// Fused CSR gather + LayerNorm. One wave per node.
// agg = sum over CSR row of M[dst]; x = z + agg/(deg+1e-12); LN(x)*gamma+beta.
__global__ __launch_bounds__(256) void gather_ln(
        const float* __restrict__ z, const float* __restrict__ Mx,
        const int* __restrict__ rowstart, const int* __restrict__ deg,
        const int* __restrict__ cdst, const float* __restrict__ gamma,
        const float* __restrict__ beta, float* __restrict__ out, int N) {
    int wid = threadIdx.x >> 6, lane = threadIdx.x & 63;
    int n = blockIdx.x * 4 + wid;
    if (n >= N) return;
    int r0 = rowstart[n], dg = deg[n];
    float a0 = 0.f, a1 = 0.f;
    for (int c = 0; c < dg; c += 64) {
        int cnt = min(64, dg - c);
        int myd = (lane < cnt) ? cdst[r0 + c + lane] : 0;
        for (int j = 0; j < cnt; ++j) {
            int d = __shfl(myd, j);
            const float* mrow = Mx + (size_t)d * 128;
            a0 += mrow[lane];
            a1 += mrow[lane + 64];
        }
    }
    float inv = 1.f / ((float)dg + 1e-12f);
    size_t base = (size_t)n * 128;
    float x0 = z[base + lane] + a0 * inv;
    float x1 = z[base + lane + 64] + a1 * inv;
    float s = x0 + x1;
#pragma unroll
    for (int off = 1; off < 64; off <<= 1) s += __shfl_xor(s, off);
    float mu = s * (1.f / 128.f);
    float d0 = x0 - mu, d1 = x1 - mu;
    float v = d0 * d0 + d1 * d1;
#pragma unroll
    for (int off = 1; off < 64; off <<= 1) v += __shfl_xor(v, off);
    float rs = rsqrtf(v * (1.f / 128.f) + 1e-5f);
    out[base + lane] = d0 * rs * gamma[lane] + beta[lane];
    out[base + lane + 64] = d1 * rs * gamma[lane + 64] + beta[lane + 64];
}

// ---------------------------------------------------------------------------
extern "C" void kernel_launch(void* const* d_in, const int* in_sizes, int n_in,
                              void* d_out, int out_size, void* d_ws, size_t ws_size,
                              hipStream_t stream) {
    const float* z     = (const float*)d_in[0];
    const int*   ei    = (const int*)d_in[1];
    const int*   et    = (const int*)d_in[2];
    const float* temb  = (const float*)d_in[3];
    const float* ew1   = (const float*)d_in[4];
    const float* eb1   = (const float*)d_in[5];
    const float* ew2   = (const float*)d_in[6];
    const float* eb2   = (const float*)d_in[7];
    const float* mw1   = (const float*)d_in[8];
    const float* mb1   = (const float*)d_in[9];
    const float* mw2   = (const float*)d_in[10];
    const float* mb2   = (const float*)d_in[11];
    const float* gamma = (const float*)d_in[12];
    const float* beta  = (const float*)d_in[13];

    const int N = in_sizes[0] / 128;
    const int E = in_sizes[2];

    char* ws = (char*)d_ws;
    size_t off = 0;
    auto take = [&](size_t b) { char* p = ws + off; off += (b + 255) & ~(size_t)255; return p; };
    float* Pa     = (float*)take((size_t)N * 128 * 4);
    float* Pb     = (float*)take((size_t)N * 128 * 4);
    float* H      = (float*)take((size_t)N * 128 * 4);
    float* Mx     = (float*)take((size_t)N * 128 * 4);
    char*  z0     = ws + off;                       // contiguous zero region
    float* ssum   = (float*)take((size_t)N * 4);
    int*   deg    = (int*)take((size_t)N * 4);
    int*   cursor = (int*)take((size_t)N * 4);
    size_t zb     = (size_t)((ws + off) - z0);
    int*   rowst  = (int*)take((size_t)N * 4);
    int*   cdst   = (int*)take((size_t)E * 4);
    float* expw   = (float*)take((size_t)E * 4);
    float* T2     = (float*)take(2 * 128 * 4);

    float* out_x = (float*)d_out;
    float* out_a = out_x + (size_t)N * 128;

    hipMemsetAsync(z0, 0, zb, stream);
    prep_t2<<<1, 256, 0, stream>>>(temb, ew1, eb1, T2);

    // CSR build
    deg_count<<<(E + 255) / 256, 256, 0, stream>>>(ei, deg, E);
    scan_deg<<<1, 1024, 0, stream>>>(deg, rowst, N);
    place_edges<<<(E + 255) / 256, 256, 0, stream>>>(ei, cursor, rowst, cdst, E);

    // node-level GEMMs
    int gb = (N + 63) / 64;
    gemm128<<<gb, 256, 0, stream>>>(z, ew1, nullptr, Pa, N, 0);             // Pa = z @ Wa
    gemm128<<<gb, 256, 0, stream>>>(z, ew1 + 128 * 128, nullptr, Pb, N, 0); // Pb = z @ Wb
    gemm128<<<gb, 256, 0, stream>>>(z, mw1, mb1, H, N, 1);                  // H = relu(z@mw1+mb1)
    gemm128<<<gb, 256, 0, stream>>>(H, mw2, mb2, Mx, N, 0);                 // M = H@mw2+mb2

    edge_mlp<<<(E + 63) / 64, 256, 0, stream>>>(z, ei, et, ew1 + 256 * 128,
                                                ew2, eb2, Pa, Pb, T2, expw, ssum, E);
    alpha_k<<<(E + 255) / 256, 256, 0, stream>>>(expw, ei, ssum, out_a, E);
    gather_ln<<<(N + 3) / 4, 256, 0, stream>>>(z, Mx, rowst, deg, cdst, gamma, beta, out_x, N);
}

// Round 8
// 467.811 us; speedup vs baseline: 2.3971x; 1.1862x over previous
//
#include <hip/hip_runtime.h>
#include <math.h>

// DIM=128, EMB=8, HID=128, N=50000, E=400000
// R6: edge branch -> bf16 MFMA (16x16x32), CSR-ordered edges, LDS-free edge kernel.
// msg branch + Pa/Pb GEMMs stay fp32 (attribute absmax delta to edge-bf16 only).

typedef short bf16x8 __attribute__((ext_vector_type(8)));
typedef float f32x4 __attribute__((ext_vector_type(4)));

__device__ inline short bf16_rne(float f) {
    unsigned u = __float_as_uint(f);
    u = (u + 0x7FFFu + ((u >> 16) & 1u)) >> 16;
    return (short)u;
}

// ---------------------------------------------------------------------------
// T2[t][j] = sum_u type_emb[t][u] * ew1[384+u][j] + eb1[j]   (folds eb1)
__global__ void prep_t2(const float* __restrict__ te, const float* __restrict__ ew1,
                        const float* __restrict__ eb1, float* __restrict__ T2) {
    int t = threadIdx.x;            // 256 threads
    int row = t >> 7, j = t & 127;
    float s = eb1[j];
#pragma unroll
    for (int u = 0; u < 8; ++u) s += te[row * 8 + u] * ew1[(384 + u) * 128 + j];
    T2[row * 128 + j] = s;
}

// ---------------------------------------------------------------------------
// Pre-pack Wc (= ew1 rows 256..383) into bf16 MFMA B-fragment order:
// Bswz[((ks*8+ct)*64 + l)*8 + j] = bf16(Wc[ks*32 + (l>>4)*8 + j][ct*16 + (l&15)])
__global__ void prep_wc_swz(const float* __restrict__ Wc, unsigned short* __restrict__ Bswz) {
    for (int idx = threadIdx.x; idx < 2048; idx += 256) {
        int ks = idx >> 9, ct = (idx >> 6) & 7, l = idx & 63;
        int kbase = ks * 32 + (l >> 4) * 8;
        int col = ct * 16 + (l & 15);
#pragma unroll
        for (int j = 0; j < 8; ++j)
            Bswz[(size_t)idx * 8 + j] =
                (unsigned short)bf16_rne(Wc[(size_t)(kbase + j) * 128 + col]);
    }
}

// ---------------------------------------------------------------------------
// deg[src[e]]++ histogram
__global__ void deg_count(const int* __restrict__ ei, int* __restrict__ deg, int E) {
    int e = blockIdx.x * 256 + threadIdx.x;
    if (e >= E) return;
    atomicAdd(&deg[ei[e]], 1);
}

// ---------------------------------------------------------------------------
// Single-block exclusive scan of deg[0..N) -> rowstart[0..N). 1024 threads.
__global__ __launch_bounds__(1024) void scan_deg(const int* __restrict__ deg,
                                                 int* __restrict__ rowstart, int N) {
    __shared__ int wsum[16];
    __shared__ int carry_s;
    const int lane = threadIdx.x & 63, wid = threadIdx.x >> 6;
    if (threadIdx.x == 0) carry_s = 0;
    __syncthreads();
    for (int base = 0; base < N; base += 1024) {
        int i = base + threadIdx.x;
        int v = (i < N) ? deg[i] : 0;
        int x = v;
#pragma unroll
        for (int off = 1; off < 64; off <<= 1) {
            int t = __shfl_up(x, off);
            if (lane >= off) x += t;
        }
        if (lane == 63) wsum[wid] = x;
        __syncthreads();
        if (wid == 0 && lane < 16) {
            int s = wsum[lane];
#pragma unroll
            for (int off = 1; off < 16; off <<= 1) {
                int t = __shfl_up(s, off);
                if (lane >= off) s += t;
            }
            wsum[lane] = s;
        }
        __syncthreads();
        int wexcl = (wid == 0) ? 0 : wsum[wid - 1];
        int carry = carry_s;
        if (i < N) rowstart[i] = carry + wexcl + x - v;
        __syncthreads();
        if (threadIdx.x == 0) carry_s = carry + wsum[15];
        __syncthreads();
    }
}

// ---------------------------------------------------------------------------
// CSR placement; also records src/etype/original-edge-id per slot.
__global__ void place_edges(const int* __restrict__ ei, const int* __restrict__ etype,
                            int* __restrict__ cursor, const int* __restrict__ rowstart,
                            int* __restrict__ cdstv, int* __restrict__ csrc,
                            int* __restrict__ cet, int* __restrict__ cperm, int E) {
    int e = blockIdx.x * 256 + threadIdx.x;
    if (e >= E) return;
    int s = ei[e], d = ei[E + e];
    int slot = rowstart[s] + atomicAdd(&cursor[s], 1);
    cdstv[slot] = d;
    csrc[slot] = s;
    cet[slot] = etype[e];
    cperm[slot] = e;
}

// ---------------------------------------------------------------------------
// Generic C[M,128] = act(A[M,128] @ B[128,128] + bias). fp32, tiled. (unchanged)
__global__ __launch_bounds__(256) void gemm128(const float* __restrict__ A,
                                               const float* __restrict__ B,
                                               const float* __restrict__ bias,
                                               float* __restrict__ C, int M, int relu) {
    __shared__ float As[64 * 132];
    __shared__ float Bs[32 * 132];
    const int t = threadIdx.x;
    const int tx = t & 15, ty = t >> 4;
    const int row0 = blockIdx.x * 64;

    {
        int r = t >> 2;
        int rr = row0 + r;
        const float* arow = A + (size_t)rr * 128;
#pragma unroll
        for (int j = 0; j < 8; ++j) {
            int c = ((t & 3) + 4 * j) * 4;
            float4 v = make_float4(0.f, 0.f, 0.f, 0.f);
            if (rr < M) v = *(const float4*)(arow + c);
            *(float4*)&As[r * 132 + c] = v;
        }
    }

    float acc[4][8];
#pragma unroll
    for (int i = 0; i < 4; ++i)
#pragma unroll
        for (int j = 0; j < 8; ++j) acc[i][j] = 0.f;

    for (int k0 = 0; k0 < 128; k0 += 32) {
        __syncthreads();
#pragma unroll
        for (int q = 0; q < 4; ++q) {
            int idx = t + 256 * q;
            int kk = idx >> 5, c4 = idx & 31;
            float4 v = *(const float4*)(B + (size_t)(k0 + kk) * 128 + c4 * 4);
            *(float4*)&Bs[kk * 132 + c4 * 4] = v;
        }
        __syncthreads();
#pragma unroll 4
        for (int kk = 0; kk < 32; ++kk) {
            float a0 = As[(ty * 4 + 0) * 132 + k0 + kk];
            float a1 = As[(ty * 4 + 1) * 132 + k0 + kk];
            float a2 = As[(ty * 4 + 2) * 132 + k0 + kk];
            float a3 = As[(ty * 4 + 3) * 132 + k0 + kk];
            float4 b0 = *(float4*)&Bs[kk * 132 + tx * 8];
            float4 b1 = *(float4*)&Bs[kk * 132 + tx * 8 + 4];
            float bb[8] = {b0.x, b0.y, b0.z, b0.w, b1.x, b1.y, b1.z, b1.w};
#pragma unroll
            for (int j = 0; j < 8; ++j) {
                acc[0][j] = fmaf(a0, bb[j], acc[0][j]);
                acc[1][j] = fmaf(a1, bb[j], acc[1][j]);
                acc[2][j] = fmaf(a2, bb[j], acc[2][j]);
                acc[3][j] = fmaf(a3, bb[j], acc[3][j]);
            }
        }
    }

    const int c0 = tx * 8;
    float bi[8] = {0, 0, 0, 0, 0, 0, 0, 0};
    if (bias) {
        float4 b0 = *(const float4*)(bias + c0);
        float4 b1 = *(const float4*)(bias + c0 + 4);
        bi[0] = b0.x; bi[1] = b0.y; bi[2] = b0.z; bi[3] = b0.w;
        bi[4] = b1.x; bi[5] = b1.y; bi[6] = b1.z; bi[7] = b1.w;
    }
#pragma unroll
    for (int i = 0; i < 4; ++i) {
        int rr = row0 + ty * 4 + i;
        if (rr >= M) continue;
        float o[8];
#pragma unroll
        for (int j = 0; j < 8; ++j) {
            o[j] = acc[i][j] + bi[j];
            if (relu) o[j] = fmaxf(o[j], 0.f);
        }
        float* crow = C + (size_t)rr * 128 + c0;
        *(float4*)crow = make_float4(o[0], o[1], o[2], o[3]);
        *(float4*)(crow + 4) = make_float4(o[4], o[5], o[6], o[7]);
    }
}

// ---------------------------------------------------------------------------
// MFMA edge kernel (CSR slot order, no LDS, no barriers).
// Per block: 64 slots. 4 waves; wave w owns D-rows w*16..w*16+15.
// h = relu(|zi-zj|@Wc + Pa[src] + Pb[dst] + T2[et]); w=sigmoid(h.ew2+eb2);
// expw[slot]=exp(w); atomic ssum[src]+=exp(w).
__global__ __launch_bounds__(256) void edge_mlp_mfma(
        const float* __restrict__ z, const int* __restrict__ csrc,
        const int* __restrict__ cdstv, const int* __restrict__ cet,
        const bf16x8* __restrict__ Bfr,          // prepacked Wc fragments
        const float* __restrict__ ew2, const float* __restrict__ eb2,
        const float* __restrict__ Pa, const float* __restrict__ Pb,
        const float* __restrict__ T2, float* __restrict__ expw,
        float* __restrict__ ssum, int E) {
    const int l = threadIdx.x & 63;
    const int wv = threadIdx.x >> 6;       // wave 0..3
    const int c = l & 15, g = l >> 4;      // frag coords
    const int slot0 = blockIdx.x * 64;

    // ---- A-side addresses: lane loads row ra = wv*16 + c of the D tile ----
    const int ra = slot0 + wv * 16 + c;
    const int sA = csrc[ra], dA = cdstv[ra];
    const float* zi = z + (size_t)sA * 128 + g * 8;
    const float* zj = z + (size_t)dA * 128 + g * 8;

    f32x4 acc[8];
#pragma unroll
    for (int ct = 0; ct < 8; ++ct)
#pragma unroll
        for (int r = 0; r < 4; ++r) acc[ct][r] = 0.f;

#pragma unroll
    for (int ks = 0; ks < 4; ++ks) {
        float4 ai0 = *(const float4*)(zi + ks * 32);
        float4 ai1 = *(const float4*)(zi + ks * 32 + 4);
        float4 aj0 = *(const float4*)(zj + ks * 32);
        float4 aj1 = *(const float4*)(zj + ks * 32 + 4);
        bf16x8 a;
        a[0] = bf16_rne(fabsf(ai0.x - aj0.x));
        a[1] = bf16_rne(fabsf(ai0.y - aj0.y));
        a[2] = bf16_rne(fabsf(ai0.z - aj0.z));
        a[3] = bf16_rne(fabsf(ai0.w - aj0.w));
        a[4] = bf16_rne(fabsf(ai1.x - aj1.x));
        a[5] = bf16_rne(fabsf(ai1.y - aj1.y));
        a[6] = bf16_rne(fabsf(ai1.z - aj1.z));
        a[7] = bf16_rne(fabsf(ai1.w - aj1.w));
#pragma unroll
        for (int ct = 0; ct < 8; ++ct) {
            bf16x8 b = Bfr[(ks * 8 + ct) * 64 + l];
            acc[ct] = __builtin_amdgcn_mfma_f32_16x16x32_bf16(a, b, acc[ct], 0, 0, 0);
        }
    }

    // ---- epilogue: D row (g*4+reg), col (ct*16+c) ----
    const int eb = slot0 + wv * 16 + g * 4;   // 4 consecutive slots for this lane group
    int se[4], de[4], tt[4];
#pragma unroll
    for (int r = 0; r < 4; ++r) {
        se[r] = csrc[eb + r];
        de[r] = cdstv[eb + r];
        tt[r] = cet[eb + r];
    }
    float s[4] = {0.f, 0.f, 0.f, 0.f};
#pragma unroll
    for (int ct = 0; ct < 8; ++ct) {
        int j = ct * 16 + c;
        float w2v = ew2[j];
#pragma unroll
        for (int r = 0; r < 4; ++r) {
            float h = acc[ct][r] + Pa[(size_t)se[r] * 128 + j]
                                 + Pb[(size_t)de[r] * 128 + j]
                                 + T2[tt[r] * 128 + j];
            s[r] = fmaf(fmaxf(h, 0.f), w2v, s[r]);
        }
    }
#pragma unroll
    for (int r = 0; r < 4; ++r) {
        s[r] += __shfl_xor(s[r], 1);
        s[r] += __shfl_xor(s[r], 2);
        s[r] += __shfl_xor(s[r], 4);
        s[r] += __shfl_xor(s[r], 8);
    }
    if (c == 0) {
        const float eb2v = eb2[0];
#pragma unroll
        for (int r = 0; r < 4; ++r) {
            float w = 1.f / (1.f + expf(-(s[r] + eb2v)));
            float ewv = expf(w);
            expw[eb + r] = ewv;
            atomicAdd(&ssum[se[r]], ewv);
        }
    }
}

// ---------------------------------------------------------------------------
// alpha (scatter back to original edge order via cperm)
__global__ void alpha_k(const float* __restrict__ expw, const int* __restrict__ csrc,
                        const int* __restrict__ cperm, const float* __restrict__ ssum,
                        float* __restrict__ oa, int E) {
    int slot = blockIdx.x * 256 + threadIdx.x;
    if (slot >= E) return;
    oa[cperm[slot]] = expw[slot] / (ssum[csrc[slot]] + 1e-12f);
}

// ---------------------------------------------------------------------------
// Fused CSR gather + LayerNorm. One wave per node. (unchanged)
__global__ __launch_bounds__(256) void gather_ln(
        const float* __restrict__ z, const float* __restrict__ Mx,
        const int* __restrict__ rowstart, const int* __restrict__ deg,
        const int* __restrict__ cdst, const float* __restrict__ gamma,
        const float* __restrict__ beta, float* __restrict__ out, int N) {
    int wid = threadIdx.x >> 6, lane = threadIdx.x & 63;
    int n = blockIdx.x * 4 + wid;
    if (n >= N) return;
    int r0 = rowstart[n], dg = deg[n];
    float a0 = 0.f, a1 = 0.f;
    for (int c = 0; c < dg; c += 64) {
        int cnt = min(64, dg - c);
        int myd = (lane < cnt) ? cdst[r0 + c + lane] : 0;
        for (int j = 0; j < cnt; ++j) {
            int d = __shfl(myd, j);
            const float* mrow = Mx + (size_t)d * 128;
            a0 += mrow[lane];
            a1 += mrow[lane + 64];
        }
    }
    float inv = 1.f / ((float)dg + 1e-12f);
    size_t base = (size_t)n * 128;
    float x0 = z[base + lane] + a0 * inv;
    float x1 = z[base + lane + 64] + a1 * inv;
    float s = x0 + x1;
#pragma unroll
    for (int off = 1; off < 64; off <<= 1) s += __shfl_xor(s, off);
    float mu = s * (1.f / 128.f);
    float d0 = x0 - mu, d1 = x1 - mu;
    float v = d0 * d0 + d1 * d1;
#pragma unroll
    for (int off = 1; off < 64; off <<= 1) v += __shfl_xor(v, off);
    float rs = rsqrtf(v * (1.f / 128.f) + 1e-5f);
    out[base + lane] = d0 * rs * gamma[lane] + beta[lane];
    out[base + lane + 64] = d1 * rs * gamma[lane + 64] + beta[lane + 64];
}

// ---------------------------------------------------------------------------
extern "C" void kernel_launch(void* const* d_in, const int* in_sizes, int n_in,
                              void* d_out, int out_size, void* d_ws, size_t ws_size,
                              hipStream_t stream) {
    const float* z     = (const float*)d_in[0];
    const int*   ei    = (const int*)d_in[1];
    const int*   et    = (const int*)d_in[2];
    const float* temb  = (const float*)d_in[3];
    const float* ew1   = (const float*)d_in[4];
    const float* eb1   = (const float*)d_in[5];
    const float* ew2   = (const float*)d_in[6];
    const float* eb2   = (const float*)d_in[7];
    const float* mw1   = (const float*)d_in[8];
    const float* mb1   = (const float*)d_in[9];
    const float* mw2   = (const float*)d_in[10];
    const float* mb2   = (const float*)d_in[11];
    const float* gamma = (const float*)d_in[12];
    const float* beta  = (const float*)d_in[13];

    const int N = in_sizes[0] / 128;
    const int E = in_sizes[2];

    char* ws = (char*)d_ws;
    size_t off = 0;
    auto take = [&](size_t b) { char* p = ws + off; off += (b + 255) & ~(size_t)255; return p; };
    float* Pa     = (float*)take((size_t)N * 128 * 4);
    float* Pb     = (float*)take((size_t)N * 128 * 4);
    float* H      = (float*)take((size_t)N * 128 * 4);
    float* Mx     = (float*)take((size_t)N * 128 * 4);
    char*  z0     = ws + off;                       // contiguous zero region
    float* ssum   = (float*)take((size_t)N * 4);
    int*   deg    = (int*)take((size_t)N * 4);
    int*   cursor = (int*)take((size_t)N * 4);
    size_t zb     = (size_t)((ws + off) - z0);
    int*   rowst  = (int*)take((size_t)N * 4);
    int*   cdstv  = (int*)take((size_t)E * 4);
    int*   csrc   = (int*)take((size_t)E * 4);
    int*   cet    = (int*)take((size_t)E * 4);
    int*   cperm  = (int*)take((size_t)E * 4);
    float* expw   = (float*)take((size_t)E * 4);
    float* T2     = (float*)take(2 * 128 * 4);
    unsigned short* Bswz = (unsigned short*)take(4 * 8 * 64 * 8 * 2);

    float* out_x = (float*)d_out;
    float* out_a = out_x + (size_t)N * 128;

    hipMemsetAsync(z0, 0, zb, stream);
    prep_t2<<<1, 256, 0, stream>>>(temb, ew1, eb1, T2);
    prep_wc_swz<<<1, 256, 0, stream>>>(ew1 + 256 * 128, Bswz);

    // CSR build
    deg_count<<<(E + 255) / 256, 256, 0, stream>>>(ei, deg, E);
    scan_deg<<<1, 1024, 0, stream>>>(deg, rowst, N);
    place_edges<<<(E + 255) / 256, 256, 0, stream>>>(ei, et, cursor, rowst,
                                                     cdstv, csrc, cet, cperm, E);

    // node-level GEMMs (fp32)
    int gb = (N + 63) / 64;
    gemm128<<<gb, 256, 0, stream>>>(z, ew1, nullptr, Pa, N, 0);             // Pa = z @ Wa
    gemm128<<<gb, 256, 0, stream>>>(z, ew1 + 128 * 128, nullptr, Pb, N, 0); // Pb = z @ Wb
    gemm128<<<gb, 256, 0, stream>>>(z, mw1, mb1, H, N, 1);                  // H = relu(z@mw1+mb1)
    gemm128<<<gb, 256, 0, stream>>>(H, mw2, mb2, Mx, N, 0);                 // M = H@mw2+mb2

    // edge branch (bf16 MFMA, CSR order)
    edge_mlp_mfma<<<E / 64, 256, 0, stream>>>(z, csrc, cdstv, cet,
                                              (const bf16x8*)Bswz, ew2, eb2,
                                              Pa, Pb, T2, expw, ssum, E);
    alpha_k<<<(E + 255) / 256, 256, 0, stream>>>(expw, csrc, cperm, ssum, out_a, E);
    gather_ln<<<(N + 3) / 4, 256, 0, stream>>>(z, Mx, rowst, deg, cdstv, gamma, beta, out_x, N);
}

// Round 9
// 391.794 us; speedup vs baseline: 2.8623x; 1.1940x over previous
//
#include <hip/hip_runtime.h>
#include <math.h>

// DIM=128, EMB=8, HID=128, N=50000, E=400000
// R9: all GEMMs -> bf16 MFMA (fp32 accumulate); int4-packed CSR; coalesced alpha;
// float2+unroll gather_ln. Edge kernel structure unchanged (verified R8).

typedef short bf16x8 __attribute__((ext_vector_type(8)));
typedef unsigned short ushort8 __attribute__((ext_vector_type(8)));
typedef float f32x4 __attribute__((ext_vector_type(4)));

__device__ inline short bf16_rne(float f) {
    unsigned u = __float_as_uint(f);
    u = (u + 0x7FFFu + ((u >> 16) & 1u)) >> 16;
    return (short)u;
}

// ---------------------------------------------------------------------------
// T2[t][j] = sum_u type_emb[t][u] * ew1[384+u][j] + eb1[j]   (folds eb1)
__global__ void prep_t2(const float* __restrict__ te, const float* __restrict__ ew1,
                        const float* __restrict__ eb1, float* __restrict__ T2) {
    int t = threadIdx.x;            // 256 threads
    int row = t >> 7, j = t & 127;
    float s = eb1[j];
#pragma unroll
    for (int u = 0; u < 8; ++u) s += te[row * 8 + u] * ew1[(384 + u) * 128 + j];
    T2[row * 128 + j] = s;
}

// ---------------------------------------------------------------------------
// Pack a 128x128 fp32 weight into bf16 MFMA B-fragment order:
// out[((ks*8+ct)*64 + l)*8 + j] = bf16(B[ks*32 + (l>>4)*8 + j][ct*16 + (l&15)])
__global__ void prep_frag(const float* __restrict__ B, unsigned short* __restrict__ out) {
    for (int idx = threadIdx.x; idx < 2048; idx += 256) {
        int ks = idx >> 9, ct = (idx >> 6) & 7, l = idx & 63;
        int kbase = ks * 32 + (l >> 4) * 8;
        int col = ct * 16 + (l & 15);
#pragma unroll
        for (int j = 0; j < 8; ++j)
            out[(size_t)idx * 8 + j] =
                (unsigned short)bf16_rne(B[(size_t)(kbase + j) * 128 + col]);
    }
}

// ---------------------------------------------------------------------------
// deg[src[e]]++ histogram
__global__ void deg_count(const int* __restrict__ ei, int* __restrict__ deg, int E) {
    int e = blockIdx.x * 256 + threadIdx.x;
    if (e >= E) return;
    atomicAdd(&deg[ei[e]], 1);
}

// ---------------------------------------------------------------------------
// Single-block exclusive scan of deg[0..N) -> rowstart[0..N). 1024 threads.
__global__ __launch_bounds__(1024) void scan_deg(const int* __restrict__ deg,
                                                 int* __restrict__ rowstart, int N) {
    __shared__ int wsum[16];
    __shared__ int carry_s;
    const int lane = threadIdx.x & 63, wid = threadIdx.x >> 6;
    if (threadIdx.x == 0) carry_s = 0;
    __syncthreads();
    for (int base = 0; base < N; base += 1024) {
        int i = base + threadIdx.x;
        int v = (i < N) ? deg[i] : 0;
        int x = v;
#pragma unroll
        for (int off = 1; off < 64; off <<= 1) {
            int t = __shfl_up(x, off);
            if (lane >= off) x += t;
        }
        if (lane == 63) wsum[wid] = x;
        __syncthreads();
        if (wid == 0 && lane < 16) {
            int s = wsum[lane];
#pragma unroll
            for (int off = 1; off < 16; off <<= 1) {
                int t = __shfl_up(s, off);
                if (lane >= off) s += t;
            }
            wsum[lane] = s;
        }
        __syncthreads();
        int wexcl = (wid == 0) ? 0 : wsum[wid - 1];
        int carry = carry_s;
        if (i < N) rowstart[i] = carry + wexcl + x - v;
        __syncthreads();
        if (threadIdx.x == 0) carry_s = carry + wsum[15];
        __syncthreads();
    }
}

// ---------------------------------------------------------------------------
// CSR placement: cinfo[slot] = {dst, src, etype, orig_edge}
__global__ void place_edges(const int* __restrict__ ei, const int* __restrict__ etype,
                            int* __restrict__ cursor, const int* __restrict__ rowstart,
                            int4* __restrict__ cinfo, int E) {
    int e = blockIdx.x * 256 + threadIdx.x;
    if (e >= E) return;
    int s = ei[e], d = ei[E + e];
    int slot = rowstart[s] + atomicAdd(&cursor[s], 1);
    cinfo[slot] = make_int4(d, s, etype[e], e);
}

// ---------------------------------------------------------------------------
// C[M,128] = act(A[M,128] @ B + bias); B prepacked bf16 frags; fp32 accum.
// a_bf16: A rows are ushort bf16; c_bf16: store C as bf16.
__global__ __launch_bounds__(256) void node_mfma(
        const void* __restrict__ Av, int a_bf16,
        const bf16x8* __restrict__ Bfr, const float* __restrict__ bias,
        void* __restrict__ Cv, int c_bf16, int relu, int M) {
    const int l = threadIdx.x & 63;
    const int wv = threadIdx.x >> 6;
    const int c = l & 15, g = l >> 4;
    const int row = blockIdx.x * 64 + wv * 16 + c;
    const int rowc = row < M ? row : M - 1;

    const float* af = (const float*)Av + (size_t)rowc * 128 + g * 8;
    const unsigned short* ah = (const unsigned short*)Av + (size_t)rowc * 128 + g * 8;

    f32x4 acc[8];
#pragma unroll
    for (int ct = 0; ct < 8; ++ct)
#pragma unroll
        for (int r = 0; r < 4; ++r) acc[ct][r] = 0.f;

#pragma unroll
    for (int ks = 0; ks < 4; ++ks) {
        bf16x8 a;
        if (a_bf16) {
            a = (bf16x8)(*(const ushort8*)(ah + ks * 32));
        } else {
            float4 x0 = *(const float4*)(af + ks * 32);
            float4 x1 = *(const float4*)(af + ks * 32 + 4);
            a[0] = bf16_rne(x0.x); a[1] = bf16_rne(x0.y);
            a[2] = bf16_rne(x0.z); a[3] = bf16_rne(x0.w);
            a[4] = bf16_rne(x1.x); a[5] = bf16_rne(x1.y);
            a[6] = bf16_rne(x1.z); a[7] = bf16_rne(x1.w);
        }
#pragma unroll
        for (int ct = 0; ct < 8; ++ct) {
            bf16x8 b = Bfr[(ks * 8 + ct) * 64 + l];
            acc[ct] = __builtin_amdgcn_mfma_f32_16x16x32_bf16(a, b, acc[ct], 0, 0, 0);
        }
    }

    // D: row = g*4 + r (within 16-row wave tile), col = ct*16 + c
#pragma unroll
    for (int r = 0; r < 4; ++r) {
        int rr = blockIdx.x * 64 + wv * 16 + g * 4 + r;
        if (rr >= M) continue;
#pragma unroll
        for (int ct = 0; ct < 8; ++ct) {
            int j = ct * 16 + c;
            float v = acc[ct][r] + (bias ? bias[j] : 0.f);
            if (relu) v = fmaxf(v, 0.f);
            if (c_bf16)
                ((unsigned short*)Cv)[(size_t)rr * 128 + j] = (unsigned short)bf16_rne(v);
            else
                ((float*)Cv)[(size_t)rr * 128 + j] = v;
        }
    }
}

// ---------------------------------------------------------------------------
// Fused Pa = z@Wa, Pb = z@Wb (reads z fragments once).
__global__ __launch_bounds__(256) void pa_pb_mfma(
        const float* __restrict__ z, const bf16x8* __restrict__ Ba,
        const bf16x8* __restrict__ Bb, float* __restrict__ Pa,
        float* __restrict__ Pb, int M) {
    const int l = threadIdx.x & 63;
    const int wv = threadIdx.x >> 6;
    const int c = l & 15, g = l >> 4;
    const int row = blockIdx.x * 64 + wv * 16 + c;
    const int rowc = row < M ? row : M - 1;
    const float* af = z + (size_t)rowc * 128 + g * 8;

    f32x4 acca[8], accb[8];
#pragma unroll
    for (int ct = 0; ct < 8; ++ct)
#pragma unroll
        for (int r = 0; r < 4; ++r) { acca[ct][r] = 0.f; accb[ct][r] = 0.f; }

#pragma unroll
    for (int ks = 0; ks < 4; ++ks) {
        float4 x0 = *(const float4*)(af + ks * 32);
        float4 x1 = *(const float4*)(af + ks * 32 + 4);
        bf16x8 a;
        a[0] = bf16_rne(x0.x); a[1] = bf16_rne(x0.y);
        a[2] = bf16_rne(x0.z); a[3] = bf16_rne(x0.w);
        a[4] = bf16_rne(x1.x); a[5] = bf16_rne(x1.y);
        a[6] = bf16_rne(x1.z); a[7] = bf16_rne(x1.w);
#pragma unroll
        for (int ct = 0; ct < 8; ++ct) {
            acca[ct] = __builtin_amdgcn_mfma_f32_16x16x32_bf16(
                a, Ba[(ks * 8 + ct) * 64 + l], acca[ct], 0, 0, 0);
            accb[ct] = __builtin_amdgcn_mfma_f32_16x16x32_bf16(
                a, Bb[(ks * 8 + ct) * 64 + l], accb[ct], 0, 0, 0);
        }
    }

#pragma unroll
    for (int r = 0; r < 4; ++r) {
        int rr = blockIdx.x * 64 + wv * 16 + g * 4 + r;
        if (rr >= M) continue;
#pragma unroll
        for (int ct = 0; ct < 8; ++ct) {
            int j = ct * 16 + c;
            Pa[(size_t)rr * 128 + j] = acca[ct][r];
            Pb[(size_t)rr * 128 + j] = accb[ct][r];
        }
    }
}

// ---------------------------------------------------------------------------
// MFMA edge kernel (CSR slot order, no LDS, no barriers). Structure verified R8.
// expw written in ORIGINAL edge order (perm scatter) so alpha_k is coalesced.
__global__ __launch_bounds__(256) void edge_mlp_mfma(
        const float* __restrict__ z, const int4* __restrict__ cinfo,
        const bf16x8* __restrict__ Bfr,
        const float* __restrict__ ew2, const float* __restrict__ eb2,
        const float* __restrict__ Pa, const float* __restrict__ Pb,
        const float* __restrict__ T2, float* __restrict__ expw,
        float* __restrict__ ssum, int E) {
    const int l = threadIdx.x & 63;
    const int wv = threadIdx.x >> 6;       // wave 0..3
    const int c = l & 15, g = l >> 4;      // frag coords
    const int slot0 = blockIdx.x * 64;

    // ---- A-side: lane loads row ra = wv*16 + c of the D tile ----
    const int ra = slot0 + wv * 16 + c;
    const int4 ciA = cinfo[ra];            // {dst, src, et, perm}
    const float* zi = z + (size_t)ciA.y * 128 + g * 8;
    const float* zj = z + (size_t)ciA.x * 128 + g * 8;

    f32x4 acc[8];
#pragma unroll
    for (int ct = 0; ct < 8; ++ct)
#pragma unroll
        for (int r = 0; r < 4; ++r) acc[ct][r] = 0.f;

#pragma unroll
    for (int ks = 0; ks < 4; ++ks) {
        float4 ai0 = *(const float4*)(zi + ks * 32);
        float4 ai1 = *(const float4*)(zi + ks * 32 + 4);
        float4 aj0 = *(const float4*)(zj + ks * 32);
        float4 aj1 = *(const float4*)(zj + ks * 32 + 4);
        bf16x8 a;
        a[0] = bf16_rne(fabsf(ai0.x - aj0.x));
        a[1] = bf16_rne(fabsf(ai0.y - aj0.y));
        a[2] = bf16_rne(fabsf(ai0.z - aj0.z));
        a[3] = bf16_rne(fabsf(ai0.w - aj0.w));
        a[4] = bf16_rne(fabsf(ai1.x - aj1.x));
        a[5] = bf16_rne(fabsf(ai1.y - aj1.y));
        a[6] = bf16_rne(fabsf(ai1.z - aj1.z));
        a[7] = bf16_rne(fabsf(ai1.w - aj1.w));
#pragma unroll
        for (int ct = 0; ct < 8; ++ct) {
            bf16x8 b = Bfr[(ks * 8 + ct) * 64 + l];
            acc[ct] = __builtin_amdgcn_mfma_f32_16x16x32_bf16(a, b, acc[ct], 0, 0, 0);
        }
    }

    // ---- epilogue: D row (g*4+r), col (ct*16+c) ----
    const int eb = slot0 + wv * 16 + g * 4;
    int4 cr[4];
#pragma unroll
    for (int r = 0; r < 4; ++r) cr[r] = cinfo[eb + r];

    float s[4] = {0.f, 0.f, 0.f, 0.f};
#pragma unroll
    for (int ct = 0; ct < 8; ++ct) {
        int j = ct * 16 + c;
        float w2v = ew2[j];
#pragma unroll
        for (int r = 0; r < 4; ++r) {
            float h = acc[ct][r] + Pa[(size_t)cr[r].y * 128 + j]
                                 + Pb[(size_t)cr[r].x * 128 + j]
                                 + T2[cr[r].z * 128 + j];
            s[r] = fmaf(fmaxf(h, 0.f), w2v, s[r]);
        }
    }
#pragma unroll
    for (int r = 0; r < 4; ++r) {
        s[r] += __shfl_xor(s[r], 1);
        s[r] += __shfl_xor(s[r], 2);
        s[r] += __shfl_xor(s[r], 4);
        s[r] += __shfl_xor(s[r], 8);
    }
    if (c == 0) {
        const float eb2v = eb2[0];
#pragma unroll
        for (int r = 0; r < 4; ++r) {
            float w = 1.f / (1.f + expf(-(s[r] + eb2v)));
            float ewv = expf(w);
            expw[cr[r].w] = ewv;            // original edge order
            atomicAdd(&ssum[cr[r].y], ewv);
        }
    }
}

// ---------------------------------------------------------------------------
// alpha in original edge order (fully coalesced except ssum gather)
__global__ void alpha_k(const float* __restrict__ expw, const int* __restrict__ ei,
                        const float* __restrict__ ssum, float* __restrict__ oa, int E) {
    int e = blockIdx.x * 256 + threadIdx.x;
    if (e >= E) return;
    oa[e] = expw[e] / (ssum[ei[e]] + 1e-12f);
}

// ---------------------------------------------------------------------------
// Fused CSR gather + LayerNorm. One wave per node; float2 lanes; 2-edge unroll.
__global__ __launch_bounds__(256) void gather_ln(
        const float* __restrict__ z, const float* __restrict__ Mx,
        const int* __restrict__ rowstart, const int* __restrict__ deg,
        const int4* __restrict__ cinfo, const float* __restrict__ gamma,
        const float* __restrict__ beta, float* __restrict__ out, int N) {
    int wid = threadIdx.x >> 6, lane = threadIdx.x & 63;
    int n = blockIdx.x * 4 + wid;
    if (n >= N) return;
    int r0 = rowstart[n], dg = deg[n];
    float2 a0 = make_float2(0.f, 0.f), a1 = make_float2(0.f, 0.f);
    for (int c = 0; c < dg; c += 64) {
        int cnt = min(64, dg - c);
        int myd = (lane < cnt) ? cinfo[r0 + c + lane].x : 0;
        int j = 0;
        for (; j + 1 < cnt; j += 2) {
            int d0 = __shfl(myd, j), d1 = __shfl(myd, j + 1);
            float2 v0 = ((const float2*)(Mx + (size_t)d0 * 128))[lane];
            float2 v1 = ((const float2*)(Mx + (size_t)d1 * 128))[lane];
            a0.x += v0.x; a0.y += v0.y;
            a1.x += v1.x; a1.y += v1.y;
        }
        if (j < cnt) {
            int d0 = __shfl(myd, j);
            float2 v0 = ((const float2*)(Mx + (size_t)d0 * 128))[lane];
            a0.x += v0.x; a0.y += v0.y;
        }
    }
    float inv = 1.f / ((float)dg + 1e-12f);
    size_t base = (size_t)n * 128;
    float2 zz = ((const float2*)(z + base))[lane];
    float x0 = zz.x + (a0.x + a1.x) * inv;
    float x1 = zz.y + (a0.y + a1.y) * inv;
    float s = x0 + x1;
#pragma unroll
    for (int off = 1; off < 64; off <<= 1) s += __shfl_xor(s, off);
    float mu = s * (1.f / 128.f);
    float d0 = x0 - mu, d1 = x1 - mu;
    float v = d0 * d0 + d1 * d1;
#pragma unroll
    for (int off = 1; off < 64; off <<= 1) v += __shfl_xor(v, off);
    float rs = rsqrtf(v * (1.f / 128.f) + 1e-5f);
    float2 gg = ((const float2*)gamma)[lane];
    float2 bb = ((const float2*)beta)[lane];
    float2 o = make_float2(d0 * rs * gg.x + bb.x, d1 * rs * gg.y + bb.y);
    ((float2*)(out + base))[lane] = o;
}

// ---------------------------------------------------------------------------
extern "C" void kernel_launch(void* const* d_in, const int* in_sizes, int n_in,
                              void* d_out, int out_size, void* d_ws, size_t ws_size,
                              hipStream_t stream) {
    const float* z     = (const float*)d_in[0];
    const int*   ei    = (const int*)d_in[1];
    const int*   et    = (const int*)d_in[2];
    const float* temb  = (const float*)d_in[3];
    const float* ew1   = (const float*)d_in[4];
    const float* eb1   = (const float*)d_in[5];
    const float* ew2   = (const float*)d_in[6];
    const float* eb2   = (const float*)d_in[7];
    const float* mw1   = (const float*)d_in[8];
    const float* mb1   = (const float*)d_in[9];
    const float* mw2   = (const float*)d_in[10];
    const float* mb2   = (const float*)d_in[11];
    const float* gamma = (const float*)d_in[12];
    const float* beta  = (const float*)d_in[13];

    const int N = in_sizes[0] / 128;
    const int E = in_sizes[2];

    char* ws = (char*)d_ws;
    size_t off = 0;
    auto take = [&](size_t b) { char* p = ws + off; off += (b + 255) & ~(size_t)255; return p; };
    float*          Pa    = (float*)take((size_t)N * 128 * 4);
    float*          Pb    = (float*)take((size_t)N * 128 * 4);
    unsigned short* Hb    = (unsigned short*)take((size_t)N * 128 * 2);
    float*          Mx    = (float*)take((size_t)N * 128 * 4);
    char*           z0    = ws + off;               // contiguous zero region
    float*          ssum  = (float*)take((size_t)N * 4);
    int*            deg   = (int*)take((size_t)N * 4);
    int*            cursor= (int*)take((size_t)N * 4);
    size_t          zb    = (size_t)((ws + off) - z0);
    int*            rowst = (int*)take((size_t)N * 4);
    int4*           cinfo = (int4*)take((size_t)E * 16);
    float*          expw  = (float*)take((size_t)E * 4);
    float*          T2    = (float*)take(2 * 128 * 4);
    unsigned short* Wap   = (unsigned short*)take(2048 * 8 * 2);
    unsigned short* Wbp   = (unsigned short*)take(2048 * 8 * 2);
    unsigned short* Wcp   = (unsigned short*)take(2048 * 8 * 2);
    unsigned short* Mw1p  = (unsigned short*)take(2048 * 8 * 2);
    unsigned short* Mw2p  = (unsigned short*)take(2048 * 8 * 2);

    float* out_x = (float*)d_out;
    float* out_a = out_x + (size_t)N * 128;

    hipMemsetAsync(z0, 0, zb, stream);
    prep_t2<<<1, 256, 0, stream>>>(temb, ew1, eb1, T2);
    prep_frag<<<1, 256, 0, stream>>>(ew1, Wap);
    prep_frag<<<1, 256, 0, stream>>>(ew1 + 128 * 128, Wbp);
    prep_frag<<<1, 256, 0, stream>>>(ew1 + 256 * 128, Wcp);
    prep_frag<<<1, 256, 0, stream>>>(mw1, Mw1p);
    prep_frag<<<1, 256, 0, stream>>>(mw2, Mw2p);

    // CSR build
    deg_count<<<(E + 255) / 256, 256, 0, stream>>>(ei, deg, E);
    scan_deg<<<1, 1024, 0, stream>>>(deg, rowst, N);
    place_edges<<<(E + 255) / 256, 256, 0, stream>>>(ei, et, cursor, rowst, cinfo, E);

    // node-level GEMMs (bf16 MFMA, fp32 accumulate)
    int gb = (N + 63) / 64;
    pa_pb_mfma<<<gb, 256, 0, stream>>>(z, (const bf16x8*)Wap, (const bf16x8*)Wbp,
                                       Pa, Pb, N);
    node_mfma<<<gb, 256, 0, stream>>>(z, 0, (const bf16x8*)Mw1p, mb1,
                                      Hb, 1, 1, N);                    // H bf16 = relu(z@mw1+mb1)
    node_mfma<<<gb, 256, 0, stream>>>(Hb, 1, (const bf16x8*)Mw2p, mb2,
                                      Mx, 0, 0, N);                    // Mx f32 = H@mw2+mb2

    // edge branch (bf16 MFMA, CSR order)
    edge_mlp_mfma<<<E / 64, 256, 0, stream>>>(z, cinfo, (const bf16x8*)Wcp, ew2, eb2,
                                              Pa, Pb, T2, expw, ssum, E);
    alpha_k<<<(E + 255) / 256, 256, 0, stream>>>(expw, ei, ssum, out_a, E);
    gather_ln<<<(N + 3) / 4, 256, 0, stream>>>(z, Mx, rowst, deg, cinfo, gamma, beta, out_x, N);
}

// Round 10
// 329.310 us; speedup vs baseline: 3.4053x; 1.1897x over previous
//
#include <hip/hip_runtime.h>
#include <math.h>

// DIM=128, EMB=8, HID=128, N=50000, E=400000
// R10: bf16 z for edge gather (written free in pa_pb_mfma); fused prep kernel;
// parallel 3-phase scan. Edge/node MFMA structure verified R8/R9.

typedef short bf16x8 __attribute__((ext_vector_type(8)));
typedef unsigned short ushort8 __attribute__((ext_vector_type(8)));
typedef float f32x4 __attribute__((ext_vector_type(4)));

__device__ inline short bf16_rne(float f) {
    unsigned u = __float_as_uint(f);
    u = (u + 0x7FFFu + ((u >> 16) & 1u)) >> 16;
    return (short)u;
}
__device__ inline float bf16_to_f(unsigned short h) {
    return __uint_as_float(((unsigned)h) << 16);
}

// ---------------------------------------------------------------------------
// Fused prep: block0 = T2 (folds eb1); blocks 1..5 pack weights to frag order:
// out[((ks*8+ct)*64 + l)*8 + j] = bf16(B[ks*32 + (l>>4)*8 + j][ct*16 + (l&15)])
__global__ void prep_all(const float* __restrict__ te, const float* __restrict__ ew1,
                         const float* __restrict__ eb1, const float* __restrict__ mw1,
                         const float* __restrict__ mw2, float* __restrict__ T2,
                         unsigned short* __restrict__ Wap, unsigned short* __restrict__ Wbp,
                         unsigned short* __restrict__ Wcp, unsigned short* __restrict__ Mw1p,
                         unsigned short* __restrict__ Mw2p) {
    int b = blockIdx.x;
    if (b == 0) {
        int t = threadIdx.x;
        int row = t >> 7, j = t & 127;
        float s = eb1[j];
#pragma unroll
        for (int u = 0; u < 8; ++u) s += te[row * 8 + u] * ew1[(384 + u) * 128 + j];
        T2[row * 128 + j] = s;
        return;
    }
    const float* src = (b == 1) ? ew1 : (b == 2) ? ew1 + 128 * 128
                      : (b == 3) ? ew1 + 256 * 128 : (b == 4) ? mw1 : mw2;
    unsigned short* dst = (b == 1) ? Wap : (b == 2) ? Wbp
                         : (b == 3) ? Wcp : (b == 4) ? Mw1p : Mw2p;
    for (int idx = threadIdx.x; idx < 2048; idx += 256) {
        int ks = idx >> 9, ct = (idx >> 6) & 7, l = idx & 63;
        int kbase = ks * 32 + (l >> 4) * 8;
        int col = ct * 16 + (l & 15);
#pragma unroll
        for (int j = 0; j < 8; ++j)
            dst[(size_t)idx * 8 + j] =
                (unsigned short)bf16_rne(src[(size_t)(kbase + j) * 128 + col]);
    }
}

// ---------------------------------------------------------------------------
__global__ void deg_count(const int* __restrict__ ei, int* __restrict__ deg, int E) {
    int e = blockIdx.x * 256 + threadIdx.x;
    if (e >= E) return;
    atomicAdd(&deg[ei[e]], 1);
}

// ---------------------------------------------------------------------------
// Parallel scan, phase 1: per-block (1024 elems) exclusive scan + block total.
__global__ __launch_bounds__(256) void scan_local(const int* __restrict__ deg,
                                                  int* __restrict__ rowstart,
                                                  int* __restrict__ partials, int N) {
    __shared__ int wtot[4];
    int b = blockIdx.x, t = threadIdx.x, lane = t & 63, wid = t >> 6;
    int i0 = b * 1024 + t * 4;
    int v0 = (i0 + 0 < N) ? deg[i0 + 0] : 0;
    int v1 = (i0 + 1 < N) ? deg[i0 + 1] : 0;
    int v2 = (i0 + 2 < N) ? deg[i0 + 2] : 0;
    int v3 = (i0 + 3 < N) ? deg[i0 + 3] : 0;
    int ts = v0 + v1 + v2 + v3;
    int inc = ts;
#pragma unroll
    for (int off = 1; off < 64; off <<= 1) {
        int u = __shfl_up(inc, off);
        if (lane >= off) inc += u;
    }
    if (lane == 63) wtot[wid] = inc;
    __syncthreads();
    int woff = 0;
    if (wid > 0) woff += wtot[0];
    if (wid > 1) woff += wtot[1];
    if (wid > 2) woff += wtot[2];
    int excl = woff + inc - ts;
    if (i0 + 0 < N) rowstart[i0 + 0] = excl;
    if (i0 + 1 < N) rowstart[i0 + 1] = excl + v0;
    if (i0 + 2 < N) rowstart[i0 + 2] = excl + v0 + v1;
    if (i0 + 3 < N) rowstart[i0 + 3] = excl + v0 + v1 + v2;
    if (t == 255) partials[b] = woff + inc;
}

// phase 2: exclusive scan of partials (nb <= 64) in one wave
__global__ void scan_partials(int* __restrict__ partials, int nb) {
    int lane = threadIdx.x;
    int v = (lane < nb) ? partials[lane] : 0;
    int inc = v;
#pragma unroll
    for (int off = 1; off < 64; off <<= 1) {
        int u = __shfl_up(inc, off);
        if (lane >= off) inc += u;
    }
    if (lane < nb) partials[lane] = inc - v;
}

// phase 3: add block offsets
__global__ void scan_add(int* __restrict__ rowstart, const int* __restrict__ partials, int N) {
    int i = blockIdx.x * 256 + threadIdx.x;
    if (i < N) rowstart[i] += partials[i >> 10];
}

// ---------------------------------------------------------------------------
// CSR placement: cinfo[slot] = {dst, src, etype, orig_edge}
__global__ void place_edges(const int* __restrict__ ei, const int* __restrict__ etype,
                            int* __restrict__ cursor, const int* __restrict__ rowstart,
                            int4* __restrict__ cinfo, int E) {
    int e = blockIdx.x * 256 + threadIdx.x;
    if (e >= E) return;
    int s = ei[e], d = ei[E + e];
    int slot = rowstart[s] + atomicAdd(&cursor[s], 1);
    cinfo[slot] = make_int4(d, s, etype[e], e);
}

// ---------------------------------------------------------------------------
// C[M,128] = act(A[M,128] @ B + bias); B prepacked bf16 frags; fp32 accum.
__global__ __launch_bounds__(256) void node_mfma(
        const void* __restrict__ Av, int a_bf16,
        const bf16x8* __restrict__ Bfr, const float* __restrict__ bias,
        void* __restrict__ Cv, int c_bf16, int relu, int M) {
    const int l = threadIdx.x & 63;
    const int wv = threadIdx.x >> 6;
    const int c = l & 15, g = l >> 4;
    const int row = blockIdx.x * 64 + wv * 16 + c;
    const int rowc = row < M ? row : M - 1;

    const float* af = (const float*)Av + (size_t)rowc * 128 + g * 8;
    const unsigned short* ah = (const unsigned short*)Av + (size_t)rowc * 128 + g * 8;

    f32x4 acc[8];
#pragma unroll
    for (int ct = 0; ct < 8; ++ct)
#pragma unroll
        for (int r = 0; r < 4; ++r) acc[ct][r] = 0.f;

#pragma unroll
    for (int ks = 0; ks < 4; ++ks) {
        bf16x8 a;
        if (a_bf16) {
            a = (bf16x8)(*(const ushort8*)(ah + ks * 32));
        } else {
            float4 x0 = *(const float4*)(af + ks * 32);
            float4 x1 = *(const float4*)(af + ks * 32 + 4);
            a[0] = bf16_rne(x0.x); a[1] = bf16_rne(x0.y);
            a[2] = bf16_rne(x0.z); a[3] = bf16_rne(x0.w);
            a[4] = bf16_rne(x1.x); a[5] = bf16_rne(x1.y);
            a[6] = bf16_rne(x1.z); a[7] = bf16_rne(x1.w);
        }
#pragma unroll
        for (int ct = 0; ct < 8; ++ct) {
            bf16x8 b = Bfr[(ks * 8 + ct) * 64 + l];
            acc[ct] = __builtin_amdgcn_mfma_f32_16x16x32_bf16(a, b, acc[ct], 0, 0, 0);
        }
    }

#pragma unroll
    for (int r = 0; r < 4; ++r) {
        int rr = blockIdx.x * 64 + wv * 16 + g * 4 + r;
        if (rr >= M) continue;
#pragma unroll
        for (int ct = 0; ct < 8; ++ct) {
            int j = ct * 16 + c;
            float v = acc[ct][r] + (bias ? bias[j] : 0.f);
            if (relu) v = fmaxf(v, 0.f);
            if (c_bf16)
                ((unsigned short*)Cv)[(size_t)rr * 128 + j] = (unsigned short)bf16_rne(v);
            else
                ((float*)Cv)[(size_t)rr * 128 + j] = v;
        }
    }
}

// ---------------------------------------------------------------------------
// Fused Pa = z@Wa, Pb = z@Wb; also emits zb16 (bf16 copy of z) for the edge kernel.
__global__ __launch_bounds__(256) void pa_pb_mfma(
        const float* __restrict__ z, const bf16x8* __restrict__ Ba,
        const bf16x8* __restrict__ Bb, float* __restrict__ Pa,
        float* __restrict__ Pb, unsigned short* __restrict__ zb16, int M) {
    const int l = threadIdx.x & 63;
    const int wv = threadIdx.x >> 6;
    const int c = l & 15, g = l >> 4;
    const int row = blockIdx.x * 64 + wv * 16 + c;
    const int rowc = row < M ? row : M - 1;
    const float* af = z + (size_t)rowc * 128 + g * 8;

    f32x4 acca[8], accb[8];
#pragma unroll
    for (int ct = 0; ct < 8; ++ct)
#pragma unroll
        for (int r = 0; r < 4; ++r) { acca[ct][r] = 0.f; accb[ct][r] = 0.f; }

#pragma unroll
    for (int ks = 0; ks < 4; ++ks) {
        float4 x0 = *(const float4*)(af + ks * 32);
        float4 x1 = *(const float4*)(af + ks * 32 + 4);
        bf16x8 a;
        a[0] = bf16_rne(x0.x); a[1] = bf16_rne(x0.y);
        a[2] = bf16_rne(x0.z); a[3] = bf16_rne(x0.w);
        a[4] = bf16_rne(x1.x); a[5] = bf16_rne(x1.y);
        a[6] = bf16_rne(x1.z); a[7] = bf16_rne(x1.w);
        if (row < M)
            *(ushort8*)(zb16 + (size_t)row * 128 + ks * 32 + g * 8) = (ushort8)a;
#pragma unroll
        for (int ct = 0; ct < 8; ++ct) {
            acca[ct] = __builtin_amdgcn_mfma_f32_16x16x32_bf16(
                a, Ba[(ks * 8 + ct) * 64 + l], acca[ct], 0, 0, 0);
            accb[ct] = __builtin_amdgcn_mfma_f32_16x16x32_bf16(
                a, Bb[(ks * 8 + ct) * 64 + l], accb[ct], 0, 0, 0);
        }
    }

#pragma unroll
    for (int r = 0; r < 4; ++r) {
        int rr = blockIdx.x * 64 + wv * 16 + g * 4 + r;
        if (rr >= M) continue;
#pragma unroll
        for (int ct = 0; ct < 8; ++ct) {
            int j = ct * 16 + c;
            Pa[(size_t)rr * 128 + j] = acca[ct][r];
            Pb[(size_t)rr * 128 + j] = accb[ct][r];
        }
    }
}

// ---------------------------------------------------------------------------
// MFMA edge kernel (CSR slot order, no LDS, no barriers). A-side from bf16 z.
__global__ __launch_bounds__(256) void edge_mlp_mfma(
        const unsigned short* __restrict__ zb16, const int4* __restrict__ cinfo,
        const bf16x8* __restrict__ Bfr,
        const float* __restrict__ ew2, const float* __restrict__ eb2,
        const float* __restrict__ Pa, const float* __restrict__ Pb,
        const float* __restrict__ T2, float* __restrict__ expw,
        float* __restrict__ ssum, int E) {
    const int l = threadIdx.x & 63;
    const int wv = threadIdx.x >> 6;       // wave 0..3
    const int c = l & 15, g = l >> 4;      // frag coords
    const int slot0 = blockIdx.x * 64;

    const int ra = slot0 + wv * 16 + c;
    const int4 ciA = cinfo[ra];            // {dst, src, et, perm}
    const unsigned short* zi = zb16 + (size_t)ciA.y * 128 + g * 8;
    const unsigned short* zj = zb16 + (size_t)ciA.x * 128 + g * 8;

    f32x4 acc[8];
#pragma unroll
    for (int ct = 0; ct < 8; ++ct)
#pragma unroll
        for (int r = 0; r < 4; ++r) acc[ct][r] = 0.f;

#pragma unroll
    for (int ks = 0; ks < 4; ++ks) {
        ushort8 ui = *(const ushort8*)(zi + ks * 32);
        ushort8 uj = *(const ushort8*)(zj + ks * 32);
        bf16x8 a;
#pragma unroll
        for (int k = 0; k < 8; ++k)
            a[k] = bf16_rne(fabsf(bf16_to_f(ui[k]) - bf16_to_f(uj[k])));
#pragma unroll
        for (int ct = 0; ct < 8; ++ct) {
            bf16x8 b = Bfr[(ks * 8 + ct) * 64 + l];
            acc[ct] = __builtin_amdgcn_mfma_f32_16x16x32_bf16(a, b, acc[ct], 0, 0, 0);
        }
    }

    // ---- epilogue: D row (g*4+r), col (ct*16+c) ----
    const int eb = slot0 + wv * 16 + g * 4;
    int4 cr[4];
#pragma unroll
    for (int r = 0; r < 4; ++r) cr[r] = cinfo[eb + r];

    float s[4] = {0.f, 0.f, 0.f, 0.f};
#pragma unroll
    for (int ct = 0; ct < 8; ++ct) {
        int j = ct * 16 + c;
        float w2v = ew2[j];
#pragma unroll
        for (int r = 0; r < 4; ++r) {
            float h = acc[ct][r] + Pa[(size_t)cr[r].y * 128 + j]
                                 + Pb[(size_t)cr[r].x * 128 + j]
                                 + T2[cr[r].z * 128 + j];
            s[r] = fmaf(fmaxf(h, 0.f), w2v, s[r]);
        }
    }
#pragma unroll
    for (int r = 0; r < 4; ++r) {
        s[r] += __shfl_xor(s[r], 1);
        s[r] += __shfl_xor(s[r], 2);
        s[r] += __shfl_xor(s[r], 4);
        s[r] += __shfl_xor(s[r], 8);
    }
    if (c == 0) {
        const float eb2v = eb2[0];
#pragma unroll
        for (int r = 0; r < 4; ++r) {
            float w = 1.f / (1.f + expf(-(s[r] + eb2v)));
            float ewv = expf(w);
            expw[cr[r].w] = ewv;            // original edge order
            atomicAdd(&ssum[cr[r].y], ewv);
        }
    }
}

// ---------------------------------------------------------------------------
__global__ void alpha_k(const float* __restrict__ expw, const int* __restrict__ ei,
                        const float* __restrict__ ssum, float* __restrict__ oa, int E) {
    int e = blockIdx.x * 256 + threadIdx.x;
    if (e >= E) return;
    oa[e] = expw[e] / (ssum[ei[e]] + 1e-12f);
}

// ---------------------------------------------------------------------------
// Fused CSR gather + LayerNorm. One wave per node; float2 lanes; 2-edge unroll.
__global__ __launch_bounds__(256) void gather_ln(
        const float* __restrict__ z, const float* __restrict__ Mx,
        const int* __restrict__ rowstart, const int* __restrict__ deg,
        const int4* __restrict__ cinfo, const float* __restrict__ gamma,
        const float* __restrict__ beta, float* __restrict__ out, int N) {
    int wid = threadIdx.x >> 6, lane = threadIdx.x & 63;
    int n = blockIdx.x * 4 + wid;
    if (n >= N) return;
    int r0 = rowstart[n], dg = deg[n];
    float2 a0 = make_float2(0.f, 0.f), a1 = make_float2(0.f, 0.f);
    for (int c = 0; c < dg; c += 64) {
        int cnt = min(64, dg - c);
        int myd = (lane < cnt) ? cinfo[r0 + c + lane].x : 0;
        int j = 0;
        for (; j + 1 < cnt; j += 2) {
            int d0 = __shfl(myd, j), d1 = __shfl(myd, j + 1);
            float2 v0 = ((const float2*)(Mx + (size_t)d0 * 128))[lane];
            float2 v1 = ((const float2*)(Mx + (size_t)d1 * 128))[lane];
            a0.x += v0.x; a0.y += v0.y;
            a1.x += v1.x; a1.y += v1.y;
        }
        if (j < cnt) {
            int d0 = __shfl(myd, j);
            float2 v0 = ((const float2*)(Mx + (size_t)d0 * 128))[lane];
            a0.x += v0.x; a0.y += v0.y;
        }
    }
    float inv = 1.f / ((float)dg + 1e-12f);
    size_t base = (size_t)n * 128;
    float2 zz = ((const float2*)(z + base))[lane];
    float x0 = zz.x + (a0.x + a1.x) * inv;
    float x1 = zz.y + (a0.y + a1.y) * inv;
    float s = x0 + x1;
#pragma unroll
    for (int off = 1; off < 64; off <<= 1) s += __shfl_xor(s, off);
    float mu = s * (1.f / 128.f);
    float d0 = x0 - mu, d1 = x1 - mu;
    float v = d0 * d0 + d1 * d1;
#pragma unroll
    for (int off = 1; off < 64; off <<= 1) v += __shfl_xor(v, off);
    float rs = rsqrtf(v * (1.f / 128.f) + 1e-5f);
    float2 gg = ((const float2*)gamma)[lane];
    float2 bb = ((const float2*)beta)[lane];
    float2 o = make_float2(d0 * rs * gg.x + bb.x, d1 * rs * gg.y + bb.y);
    ((float2*)(out + base))[lane] = o;
}

// ---------------------------------------------------------------------------
extern "C" void kernel_launch(void* const* d_in, const int* in_sizes, int n_in,
                              void* d_out, int out_size, void* d_ws, size_t ws_size,
                              hipStream_t stream) {
    const float* z     = (const float*)d_in[0];
    const int*   ei    = (const int*)d_in[1];
    const int*   et    = (const int*)d_in[2];
    const float* temb  = (const float*)d_in[3];
    const float* ew1   = (const float*)d_in[4];
    const float* eb1   = (const float*)d_in[5];
    const float* ew2   = (const float*)d_in[6];
    const float* eb2   = (const float*)d_in[7];
    const float* mw1   = (const float*)d_in[8];
    const float* mb1   = (const float*)d_in[9];
    const float* mw2   = (const float*)d_in[10];
    const float* mb2   = (const float*)d_in[11];
    const float* gamma = (const float*)d_in[12];
    const float* beta  = (const float*)d_in[13];

    const int N = in_sizes[0] / 128;
    const int E = in_sizes[2];

    char* ws = (char*)d_ws;
    size_t off = 0;
    auto take = [&](size_t b) { char* p = ws + off; off += (b + 255) & ~(size_t)255; return p; };
    float*          Pa    = (float*)take((size_t)N * 128 * 4);
    float*          Pb    = (float*)take((size_t)N * 128 * 4);
    unsigned short* Hb    = (unsigned short*)take((size_t)N * 128 * 2);
    float*          Mx    = (float*)take((size_t)N * 128 * 4);
    unsigned short* zb16  = (unsigned short*)take((size_t)N * 128 * 2);
    char*           z0    = ws + off;               // contiguous zero region
    float*          ssum  = (float*)take((size_t)N * 4);
    int*            deg   = (int*)take((size_t)N * 4);
    int*            cursor= (int*)take((size_t)N * 4);
    size_t          zb    = (size_t)((ws + off) - z0);
    int*            rowst = (int*)take((size_t)N * 4);
    int*            parts = (int*)take(256 * 4);
    int4*           cinfo = (int4*)take((size_t)E * 16);
    float*          expw  = (float*)take((size_t)E * 4);
    float*          T2    = (float*)take(2 * 128 * 4);
    unsigned short* Wap   = (unsigned short*)take(2048 * 8 * 2);
    unsigned short* Wbp   = (unsigned short*)take(2048 * 8 * 2);
    unsigned short* Wcp   = (unsigned short*)take(2048 * 8 * 2);
    unsigned short* Mw1p  = (unsigned short*)take(2048 * 8 * 2);
    unsigned short* Mw2p  = (unsigned short*)take(2048 * 8 * 2);

    float* out_x = (float*)d_out;
    float* out_a = out_x + (size_t)N * 128;

    hipMemsetAsync(z0, 0, zb, stream);
    prep_all<<<6, 256, 0, stream>>>(temb, ew1, eb1, mw1, mw2,
                                    T2, Wap, Wbp, Wcp, Mw1p, Mw2p);

    // CSR build (parallel scan)
    const int nb = (N + 1023) / 1024;     // 49 <= 64
    deg_count<<<(E + 255) / 256, 256, 0, stream>>>(ei, deg, E);
    scan_local<<<nb, 256, 0, stream>>>(deg, rowst, parts, N);
    scan_partials<<<1, 64, 0, stream>>>(parts, nb);
    scan_add<<<(N + 255) / 256, 256, 0, stream>>>(rowst, parts, N);
    place_edges<<<(E + 255) / 256, 256, 0, stream>>>(ei, et, cursor, rowst, cinfo, E);

    // node-level GEMMs (bf16 MFMA, fp32 accumulate)
    int gb = (N + 63) / 64;
    pa_pb_mfma<<<gb, 256, 0, stream>>>(z, (const bf16x8*)Wap, (const bf16x8*)Wbp,
                                       Pa, Pb, zb16, N);
    node_mfma<<<gb, 256, 0, stream>>>(z, 0, (const bf16x8*)Mw1p, mb1,
                                      Hb, 1, 1, N);                    // H bf16
    node_mfma<<<gb, 256, 0, stream>>>(Hb, 1, (const bf16x8*)Mw2p, mb2,
                                      Mx, 0, 0, N);                    // Mx f32

    // edge branch (bf16 MFMA, CSR order, bf16 z gather)
    edge_mlp_mfma<<<E / 64, 256, 0, stream>>>(zb16, cinfo, (const bf16x8*)Wcp, ew2, eb2,
                                              Pa, Pb, T2, expw, ssum, E);
    alpha_k<<<(E + 255) / 256, 256, 0, stream>>>(expw, ei, ssum, out_a, E);
    gather_ln<<<(N + 3) / 4, 256, 0, stream>>>(z, Mx, rowst, deg, cinfo, gamma, beta, out_x, N);
}

// Round 11
// 326.122 us; speedup vs baseline: 3.4386x; 1.0098x over previous
//
#include <hip/hip_runtime.h>
#include <math.h>

// DIM=128, EMB=8, HID=128, N=50000, E=400000
// R11: Pa/Pb stored bf16 (edge epilogue gather halved); node phase fused into
// one kernel (z read once, H via LDS transpose, no Hb round-trip).
// Edge/node MFMA fragment scheme verified R8/R9/R10.

typedef short bf16x8 __attribute__((ext_vector_type(8)));
typedef unsigned short ushort8 __attribute__((ext_vector_type(8)));
typedef float f32x4 __attribute__((ext_vector_type(4)));

__device__ inline short bf16_rne(float f) {
    unsigned u = __float_as_uint(f);
    u = (u + 0x7FFFu + ((u >> 16) & 1u)) >> 16;
    return (short)u;
}
__device__ inline float bf16_to_f(unsigned short h) {
    return __uint_as_float(((unsigned)h) << 16);
}

// ---------------------------------------------------------------------------
// Fused prep: block0 = T2 (folds eb1); blocks 1..5 pack weights to frag order:
// out[((ks*8+ct)*64 + l)*8 + j] = bf16(B[ks*32 + (l>>4)*8 + j][ct*16 + (l&15)])
__global__ void prep_all(const float* __restrict__ te, const float* __restrict__ ew1,
                         const float* __restrict__ eb1, const float* __restrict__ mw1,
                         const float* __restrict__ mw2, float* __restrict__ T2,
                         unsigned short* __restrict__ Wap, unsigned short* __restrict__ Wbp,
                         unsigned short* __restrict__ Wcp, unsigned short* __restrict__ Mw1p,
                         unsigned short* __restrict__ Mw2p) {
    int b = blockIdx.x;
    if (b == 0) {
        int t = threadIdx.x;
        int row = t >> 7, j = t & 127;
        float s = eb1[j];
#pragma unroll
        for (int u = 0; u < 8; ++u) s += te[row * 8 + u] * ew1[(384 + u) * 128 + j];
        T2[row * 128 + j] = s;
        return;
    }
    const float* src = (b == 1) ? ew1 : (b == 2) ? ew1 + 128 * 128
                      : (b == 3) ? ew1 + 256 * 128 : (b == 4) ? mw1 : mw2;
    unsigned short* dst = (b == 1) ? Wap : (b == 2) ? Wbp
                         : (b == 3) ? Wcp : (b == 4) ? Mw1p : Mw2p;
    for (int idx = threadIdx.x; idx < 2048; idx += 256) {
        int ks = idx >> 9, ct = (idx >> 6) & 7, l = idx & 63;
        int kbase = ks * 32 + (l >> 4) * 8;
        int col = ct * 16 + (l & 15);
#pragma unroll
        for (int j = 0; j < 8; ++j)
            dst[(size_t)idx * 8 + j] =
                (unsigned short)bf16_rne(src[(size_t)(kbase + j) * 128 + col]);
    }
}

// ---------------------------------------------------------------------------
__global__ void deg_count(const int* __restrict__ ei, int* __restrict__ deg, int E) {
    int e = blockIdx.x * 256 + threadIdx.x;
    if (e >= E) return;
    atomicAdd(&deg[ei[e]], 1);
}

// ---------------------------------------------------------------------------
// Parallel scan, phase 1: per-block (1024 elems) exclusive scan + block total.
__global__ __launch_bounds__(256) void scan_local(const int* __restrict__ deg,
                                                  int* __restrict__ rowstart,
                                                  int* __restrict__ partials, int N) {
    __shared__ int wtot[4];
    int b = blockIdx.x, t = threadIdx.x, lane = t & 63, wid = t >> 6;
    int i0 = b * 1024 + t * 4;
    int v0 = (i0 + 0 < N) ? deg[i0 + 0] : 0;
    int v1 = (i0 + 1 < N) ? deg[i0 + 1] : 0;
    int v2 = (i0 + 2 < N) ? deg[i0 + 2] : 0;
    int v3 = (i0 + 3 < N) ? deg[i0 + 3] : 0;
    int ts = v0 + v1 + v2 + v3;
    int inc = ts;
#pragma unroll
    for (int off = 1; off < 64; off <<= 1) {
        int u = __shfl_up(inc, off);
        if (lane >= off) inc += u;
    }
    if (lane == 63) wtot[wid] = inc;
    __syncthreads();
    int woff = 0;
    if (wid > 0) woff += wtot[0];
    if (wid > 1) woff += wtot[1];
    if (wid > 2) woff += wtot[2];
    int excl = woff + inc - ts;
    if (i0 + 0 < N) rowstart[i0 + 0] = excl;
    if (i0 + 1 < N) rowstart[i0 + 1] = excl + v0;
    if (i0 + 2 < N) rowstart[i0 + 2] = excl + v0 + v1;
    if (i0 + 3 < N) rowstart[i0 + 3] = excl + v0 + v1 + v2;
    if (t == 255) partials[b] = woff + inc;
}

// phase 2: exclusive scan of partials (nb <= 64) in one wave
__global__ void scan_partials(int* __restrict__ partials, int nb) {
    int lane = threadIdx.x;
    int v = (lane < nb) ? partials[lane] : 0;
    int inc = v;
#pragma unroll
    for (int off = 1; off < 64; off <<= 1) {
        int u = __shfl_up(inc, off);
        if (lane >= off) inc += u;
    }
    if (lane < nb) partials[lane] = inc - v;
}

// phase 3: add block offsets
__global__ void scan_add(int* __restrict__ rowstart, const int* __restrict__ partials, int N) {
    int i = blockIdx.x * 256 + threadIdx.x;
    if (i < N) rowstart[i] += partials[i >> 10];
}

// ---------------------------------------------------------------------------
// CSR placement: cinfo[slot] = {dst, src, etype, orig_edge}
__global__ void place_edges(const int* __restrict__ ei, const int* __restrict__ etype,
                            int* __restrict__ cursor, const int* __restrict__ rowstart,
                            int4* __restrict__ cinfo, int E) {
    int e = blockIdx.x * 256 + threadIdx.x;
    if (e >= E) return;
    int s = ei[e], d = ei[E + e];
    int slot = rowstart[s] + atomicAdd(&cursor[s], 1);
    cinfo[slot] = make_int4(d, s, etype[e], e);
}

// ---------------------------------------------------------------------------
// Fused node phase: reads z fragments once.
//   Pa = bf16(z@Wa), Pb = bf16(z@Wb), zb16 = bf16(z),
//   H  = bf16(relu(z@mw1+mb1))   (LDS only),
//   Mx = f32(H@mw2+mb2).
__global__ __launch_bounds__(256) void node_all(
        const float* __restrict__ z, const bf16x8* __restrict__ Ba,
        const bf16x8* __restrict__ Bb, const bf16x8* __restrict__ Bm1,
        const bf16x8* __restrict__ Bm2, const float* __restrict__ mb1,
        const float* __restrict__ mb2, unsigned short* __restrict__ Pa,
        unsigned short* __restrict__ Pb, unsigned short* __restrict__ zb16,
        float* __restrict__ Mx, int M) {
    __shared__ unsigned short Hs[64][136];   // +8 pad: conflict-light transpose
    const int l = threadIdx.x & 63;
    const int wv = threadIdx.x >> 6;
    const int c = l & 15, g = l >> 4;
    const int row = blockIdx.x * 64 + wv * 16 + c;
    const int rowc = row < M ? row : M - 1;
    const float* af = z + (size_t)rowc * 128 + g * 8;

    f32x4 acca[8], accb[8], acch[8];
#pragma unroll
    for (int ct = 0; ct < 8; ++ct)
#pragma unroll
        for (int r = 0; r < 4; ++r) { acca[ct][r] = 0.f; accb[ct][r] = 0.f; acch[ct][r] = 0.f; }

    bf16x8 afrag[4];
#pragma unroll
    for (int ks = 0; ks < 4; ++ks) {
        float4 x0 = *(const float4*)(af + ks * 32);
        float4 x1 = *(const float4*)(af + ks * 32 + 4);
        bf16x8 a;
        a[0] = bf16_rne(x0.x); a[1] = bf16_rne(x0.y);
        a[2] = bf16_rne(x0.z); a[3] = bf16_rne(x0.w);
        a[4] = bf16_rne(x1.x); a[5] = bf16_rne(x1.y);
        a[6] = bf16_rne(x1.z); a[7] = bf16_rne(x1.w);
        afrag[ks] = a;
        if (row < M)
            *(ushort8*)(zb16 + (size_t)row * 128 + ks * 32 + g * 8) = (ushort8)a;
    }
#pragma unroll
    for (int ks = 0; ks < 4; ++ks) {
#pragma unroll
        for (int ct = 0; ct < 8; ++ct) {
            acca[ct] = __builtin_amdgcn_mfma_f32_16x16x32_bf16(
                afrag[ks], Ba[(ks * 8 + ct) * 64 + l], acca[ct], 0, 0, 0);
            accb[ct] = __builtin_amdgcn_mfma_f32_16x16x32_bf16(
                afrag[ks], Bb[(ks * 8 + ct) * 64 + l], accb[ct], 0, 0, 0);
            acch[ct] = __builtin_amdgcn_mfma_f32_16x16x32_bf16(
                afrag[ks], Bm1[(ks * 8 + ct) * 64 + l], acch[ct], 0, 0, 0);
        }
    }

    // write Pa/Pb (bf16) + stage H into LDS (bf16, relu+bias applied)
#pragma unroll
    for (int r = 0; r < 4; ++r) {
        int rr = blockIdx.x * 64 + wv * 16 + g * 4 + r;
        bool ok = rr < M;
#pragma unroll
        for (int ct = 0; ct < 8; ++ct) {
            int j = ct * 16 + c;
            if (ok) {
                Pa[(size_t)rr * 128 + j] = (unsigned short)bf16_rne(acca[ct][r]);
                Pb[(size_t)rr * 128 + j] = (unsigned short)bf16_rne(accb[ct][r]);
            }
            Hs[wv * 16 + g * 4 + r][j] =
                (unsigned short)bf16_rne(fmaxf(acch[ct][r] + mb1[j], 0.f));
        }
    }
    __syncthreads();

    // Mx = H@mw2 + mb2  (A-frags straight from LDS rows)
    f32x4 accm[8];
#pragma unroll
    for (int ct = 0; ct < 8; ++ct)
#pragma unroll
        for (int r = 0; r < 4; ++r) accm[ct][r] = 0.f;
#pragma unroll
    for (int ks = 0; ks < 4; ++ks) {
        bf16x8 a = (bf16x8)(*(const ushort8*)&Hs[wv * 16 + c][ks * 32 + g * 8]);
#pragma unroll
        for (int ct = 0; ct < 8; ++ct)
            accm[ct] = __builtin_amdgcn_mfma_f32_16x16x32_bf16(
                a, Bm2[(ks * 8 + ct) * 64 + l], accm[ct], 0, 0, 0);
    }
#pragma unroll
    for (int r = 0; r < 4; ++r) {
        int rr = blockIdx.x * 64 + wv * 16 + g * 4 + r;
        if (rr >= M) continue;
#pragma unroll
        for (int ct = 0; ct < 8; ++ct) {
            int j = ct * 16 + c;
            Mx[(size_t)rr * 128 + j] = accm[ct][r] + mb2[j];
        }
    }
}

// ---------------------------------------------------------------------------
// MFMA edge kernel (CSR slot order, no LDS, no barriers). bf16 z + bf16 Pa/Pb.
__global__ __launch_bounds__(256) void edge_mlp_mfma(
        const unsigned short* __restrict__ zb16, const int4* __restrict__ cinfo,
        const bf16x8* __restrict__ Bfr,
        const float* __restrict__ ew2, const float* __restrict__ eb2,
        const unsigned short* __restrict__ Pa, const unsigned short* __restrict__ Pb,
        const float* __restrict__ T2, float* __restrict__ expw,
        float* __restrict__ ssum, int E) {
    const int l = threadIdx.x & 63;
    const int wv = threadIdx.x >> 6;       // wave 0..3
    const int c = l & 15, g = l >> 4;      // frag coords
    const int slot0 = blockIdx.x * 64;

    const int ra = slot0 + wv * 16 + c;
    const int4 ciA = cinfo[ra];            // {dst, src, et, perm}
    const unsigned short* zi = zb16 + (size_t)ciA.y * 128 + g * 8;
    const unsigned short* zj = zb16 + (size_t)ciA.x * 128 + g * 8;

    f32x4 acc[8];
#pragma unroll
    for (int ct = 0; ct < 8; ++ct)
#pragma unroll
        for (int r = 0; r < 4; ++r) acc[ct][r] = 0.f;

#pragma unroll
    for (int ks = 0; ks < 4; ++ks) {
        ushort8 ui = *(const ushort8*)(zi + ks * 32);
        ushort8 uj = *(const ushort8*)(zj + ks * 32);
        bf16x8 a;
#pragma unroll
        for (int k = 0; k < 8; ++k)
            a[k] = bf16_rne(fabsf(bf16_to_f(ui[k]) - bf16_to_f(uj[k])));
#pragma unroll
        for (int ct = 0; ct < 8; ++ct) {
            bf16x8 b = Bfr[(ks * 8 + ct) * 64 + l];
            acc[ct] = __builtin_amdgcn_mfma_f32_16x16x32_bf16(a, b, acc[ct], 0, 0, 0);
        }
    }

    // ---- epilogue: D row (g*4+r), col (ct*16+c) ----
    const int eb = slot0 + wv * 16 + g * 4;
    int4 cr[4];
#pragma unroll
    for (int r = 0; r < 4; ++r) cr[r] = cinfo[eb + r];

    float s[4] = {0.f, 0.f, 0.f, 0.f};
#pragma unroll
    for (int ct = 0; ct < 8; ++ct) {
        int j = ct * 16 + c;
        float w2v = ew2[j];
#pragma unroll
        for (int r = 0; r < 4; ++r) {
            float h = acc[ct][r] + bf16_to_f(Pa[(size_t)cr[r].y * 128 + j])
                                 + bf16_to_f(Pb[(size_t)cr[r].x * 128 + j])
                                 + T2[cr[r].z * 128 + j];
            s[r] = fmaf(fmaxf(h, 0.f), w2v, s[r]);
        }
    }
#pragma unroll
    for (int r = 0; r < 4; ++r) {
        s[r] += __shfl_xor(s[r], 1);
        s[r] += __shfl_xor(s[r], 2);
        s[r] += __shfl_xor(s[r], 4);
        s[r] += __shfl_xor(s[r], 8);
    }
    if (c == 0) {
        const float eb2v = eb2[0];
#pragma unroll
        for (int r = 0; r < 4; ++r) {
            float w = 1.f / (1.f + expf(-(s[r] + eb2v)));
            float ewv = expf(w);
            expw[cr[r].w] = ewv;            // original edge order
            atomicAdd(&ssum[cr[r].y], ewv);
        }
    }
}

// ---------------------------------------------------------------------------
__global__ void alpha_k(const float* __restrict__ expw, const int* __restrict__ ei,
                        const float* __restrict__ ssum, float* __restrict__ oa, int E) {
    int e = blockIdx.x * 256 + threadIdx.x;
    if (e >= E) return;
    oa[e] = expw[e] / (ssum[ei[e]] + 1e-12f);
}

// ---------------------------------------------------------------------------
// Fused CSR gather + LayerNorm. One wave per node; float2 lanes; 2-edge unroll.
__global__ __launch_bounds__(256) void gather_ln(
        const float* __restrict__ z, const float* __restrict__ Mx,
        const int* __restrict__ rowstart, const int* __restrict__ deg,
        const int4* __restrict__ cinfo, const float* __restrict__ gamma,
        const float* __restrict__ beta, float* __restrict__ out, int N) {
    int wid = threadIdx.x >> 6, lane = threadIdx.x & 63;
    int n = blockIdx.x * 4 + wid;
    if (n >= N) return;
    int r0 = rowstart[n], dg = deg[n];
    float2 a0 = make_float2(0.f, 0.f), a1 = make_float2(0.f, 0.f);
    for (int c = 0; c < dg; c += 64) {
        int cnt = min(64, dg - c);
        int myd = (lane < cnt) ? cinfo[r0 + c + lane].x : 0;
        int j = 0;
        for (; j + 1 < cnt; j += 2) {
            int d0 = __shfl(myd, j), d1 = __shfl(myd, j + 1);
            float2 v0 = ((const float2*)(Mx + (size_t)d0 * 128))[lane];
            float2 v1 = ((const float2*)(Mx + (size_t)d1 * 128))[lane];
            a0.x += v0.x; a0.y += v0.y;
            a1.x += v1.x; a1.y += v1.y;
        }
        if (j < cnt) {
            int d0 = __shfl(myd, j);
            float2 v0 = ((const float2*)(Mx + (size_t)d0 * 128))[lane];
            a0.x += v0.x; a0.y += v0.y;
        }
    }
    float inv = 1.f / ((float)dg + 1e-12f);
    size_t base = (size_t)n * 128;
    float2 zz = ((const float2*)(z + base))[lane];
    float x0 = zz.x + (a0.x + a1.x) * inv;
    float x1 = zz.y + (a0.y + a1.y) * inv;
    float s = x0 + x1;
#pragma unroll
    for (int off = 1; off < 64; off <<= 1) s += __shfl_xor(s, off);
    float mu = s * (1.f / 128.f);
    float d0 = x0 - mu, d1 = x1 - mu;
    float v = d0 * d0 + d1 * d1;
#pragma unroll
    for (int off = 1; off < 64; off <<= 1) v += __shfl_xor(v, off);
    float rs = rsqrtf(v * (1.f / 128.f) + 1e-5f);
    float2 gg = ((const float2*)gamma)[lane];
    float2 bb = ((const float2*)beta)[lane];
    float2 o = make_float2(d0 * rs * gg.x + bb.x, d1 * rs * gg.y + bb.y);
    ((float2*)(out + base))[lane] = o;
}

// ---------------------------------------------------------------------------
extern "C" void kernel_launch(void* const* d_in, const int* in_sizes, int n_in,
                              void* d_out, int out_size, void* d_ws, size_t ws_size,
                              hipStream_t stream) {
    const float* z     = (const float*)d_in[0];
    const int*   ei    = (const int*)d_in[1];
    const int*   et    = (const int*)d_in[2];
    const float* temb  = (const float*)d_in[3];
    const float* ew1   = (const float*)d_in[4];
    const float* eb1   = (const float*)d_in[5];
    const float* ew2   = (const float*)d_in[6];
    const float* eb2   = (const float*)d_in[7];
    const float* mw1   = (const float*)d_in[8];
    const float* mb1   = (const float*)d_in[9];
    const float* mw2   = (const float*)d_in[10];
    const float* mb2   = (const float*)d_in[11];
    const float* gamma = (const float*)d_in[12];
    const float* beta  = (const float*)d_in[13];

    const int N = in_sizes[0] / 128;
    const int E = in_sizes[2];

    char* ws = (char*)d_ws;
    size_t off = 0;
    auto take = [&](size_t b) { char* p = ws + off; off += (b + 255) & ~(size_t)255; return p; };
    unsigned short* Pa    = (unsigned short*)take((size_t)N * 128 * 2);
    unsigned short* Pb    = (unsigned short*)take((size_t)N * 128 * 2);
    unsigned short* zb16  = (unsigned short*)take((size_t)N * 128 * 2);
    float*          Mx    = (float*)take((size_t)N * 128 * 4);
    char*           z0    = ws + off;               // contiguous zero region
    float*          ssum  = (float*)take((size_t)N * 4);
    int*            deg   = (int*)take((size_t)N * 4);
    int*            cursor= (int*)take((size_t)N * 4);
    size_t          zb    = (size_t)((ws + off) - z0);
    int*            rowst = (int*)take((size_t)N * 4);
    int*            parts = (int*)take(256 * 4);
    int4*           cinfo = (int4*)take((size_t)E * 16);
    float*          expw  = (float*)take((size_t)E * 4);
    float*          T2    = (float*)take(2 * 128 * 4);
    unsigned short* Wap   = (unsigned short*)take(2048 * 8 * 2);
    unsigned short* Wbp   = (unsigned short*)take(2048 * 8 * 2);
    unsigned short* Wcp   = (unsigned short*)take(2048 * 8 * 2);
    unsigned short* Mw1p  = (unsigned short*)take(2048 * 8 * 2);
    unsigned short* Mw2p  = (unsigned short*)take(2048 * 8 * 2);

    float* out_x = (float*)d_out;
    float* out_a = out_x + (size_t)N * 128;

    hipMemsetAsync(z0, 0, zb, stream);
    prep_all<<<6, 256, 0, stream>>>(temb, ew1, eb1, mw1, mw2,
                                    T2, Wap, Wbp, Wcp, Mw1p, Mw2p);

    // CSR build (parallel scan)
    const int nb = (N + 1023) / 1024;     // 49 <= 64
    deg_count<<<(E + 255) / 256, 256, 0, stream>>>(ei, deg, E);
    scan_local<<<nb, 256, 0, stream>>>(deg, rowst, parts, N);
    scan_partials<<<1, 64, 0, stream>>>(parts, nb);
    scan_add<<<(N + 255) / 256, 256, 0, stream>>>(rowst, parts, N);
    place_edges<<<(E + 255) / 256, 256, 0, stream>>>(ei, et, cursor, rowst, cinfo, E);

    // fused node phase (z read once)
    int gb = (N + 63) / 64;
    node_all<<<gb, 256, 0, stream>>>(z, (const bf16x8*)Wap, (const bf16x8*)Wbp,
                                     (const bf16x8*)Mw1p, (const bf16x8*)Mw2p,
                                     mb1, mb2, Pa, Pb, zb16, Mx, N);

    // edge branch (bf16 MFMA, CSR order, bf16 gathers)
    edge_mlp_mfma<<<E / 64, 256, 0, stream>>>(zb16, cinfo, (const bf16x8*)Wcp, ew2, eb2,
                                              Pa, Pb, T2, expw, ssum, E);
    alpha_k<<<(E + 255) / 256, 256, 0, stream>>>(expw, ei, ssum, out_a, E);
    gather_ln<<<(N + 3) / 4, 256, 0, stream>>>(z, Mx, rowst, deg, cinfo, gamma, beta, out_x, N);
}

// Round 13
// 297.606 us; speedup vs baseline: 3.7681x; 1.0958x over previous
//
#include <hip/hip_runtime.h>
#include <math.h>

// DIM=128, EMB=8, HID=128, N=50000, E=400000
// R12: permuted MFMA column mapping (D col (ct,c) -> original col c*8+ct) so each
// thread owns 8 CONTIGUOUS output columns -> vectorized Pa/Pb/T2/Hs/Mx access.
// Pure layout change; MFMA fragment scheme verified R8-R11.

typedef short bf16x8 __attribute__((ext_vector_type(8)));
typedef unsigned short ushort8 __attribute__((ext_vector_type(8)));
typedef float f32x4 __attribute__((ext_vector_type(4)));

__device__ inline short bf16_rne(float f) {
    unsigned u = __float_as_uint(f);
    u = (u + 0x7FFFu + ((u >> 16) & 1u)) >> 16;
    return (short)u;
}
__device__ inline float bf16_to_f(unsigned short h) {
    return __uint_as_float(((unsigned)h) << 16);
}

// ---------------------------------------------------------------------------
// Fused prep: block0 = T2 (folds eb1); blocks 1..5 pack weights to frag order
// with INTERLEAVED column permutation:
// out[((ks*8+ct)*64 + l)*8 + j] = bf16(B[ks*32 + (l>>4)*8 + j][(l&15)*8 + ct])
__global__ void prep_all(const float* __restrict__ te, const float* __restrict__ ew1,
                         const float* __restrict__ eb1, const float* __restrict__ mw1,
                         const float* __restrict__ mw2, float* __restrict__ T2,
                         unsigned short* __restrict__ Wap, unsigned short* __restrict__ Wbp,
                         unsigned short* __restrict__ Wcp, unsigned short* __restrict__ Mw1p,
                         unsigned short* __restrict__ Mw2p) {
    int b = blockIdx.x;
    if (b == 0) {
        int t = threadIdx.x;
        int row = t >> 7, j = t & 127;
        float s = eb1[j];
#pragma unroll
        for (int u = 0; u < 8; ++u) s += te[row * 8 + u] * ew1[(384 + u) * 128 + j];
        T2[row * 128 + j] = s;
        return;
    }
    const float* src = (b == 1) ? ew1 : (b == 2) ? ew1 + 128 * 128
                      : (b == 3) ? ew1 + 256 * 128 : (b == 4) ? mw1 : mw2;
    unsigned short* dst = (b == 1) ? Wap : (b == 2) ? Wbp
                         : (b == 3) ? Wcp : (b == 4) ? Mw1p : Mw2p;
    for (int idx = threadIdx.x; idx < 2048; idx += 256) {
        int ks = idx >> 9, ct = (idx >> 6) & 7, l = idx & 63;
        int kbase = ks * 32 + (l >> 4) * 8;
        int col = (l & 15) * 8 + ct;          // permuted mapping
#pragma unroll
        for (int j = 0; j < 8; ++j)
            dst[(size_t)idx * 8 + j] =
                (unsigned short)bf16_rne(src[(size_t)(kbase + j) * 128 + col]);
    }
}

// ---------------------------------------------------------------------------
__global__ void deg_count(const int* __restrict__ ei, int* __restrict__ deg, int E) {
    int e = blockIdx.x * 256 + threadIdx.x;
    if (e >= E) return;
    atomicAdd(&deg[ei[e]], 1);
}

// ---------------------------------------------------------------------------
// Parallel scan, phase 1: per-block (1024 elems) exclusive scan + block total.
__global__ __launch_bounds__(256) void scan_local(const int* __restrict__ deg,
                                                  int* __restrict__ rowstart,
                                                  int* __restrict__ partials, int N) {
    __shared__ int wtot[4];
    int b = blockIdx.x, t = threadIdx.x, lane = t & 63, wid = t >> 6;
    int i0 = b * 1024 + t * 4;
    int v0 = (i0 + 0 < N) ? deg[i0 + 0] : 0;
    int v1 = (i0 + 1 < N) ? deg[i0 + 1] : 0;
    int v2 = (i0 + 2 < N) ? deg[i0 + 2] : 0;
    int v3 = (i0 + 3 < N) ? deg[i0 + 3] : 0;
    int ts = v0 + v1 + v2 + v3;
    int inc = ts;
#pragma unroll
    for (int off = 1; off < 64; off <<= 1) {
        int u = __shfl_up(inc, off);
        if (lane >= off) inc += u;
    }
    if (lane == 63) wtot[wid] = inc;
    __syncthreads();
    int woff = 0;
    if (wid > 0) woff += wtot[0];
    if (wid > 1) woff += wtot[1];
    if (wid > 2) woff += wtot[2];
    int excl = woff + inc - ts;
    if (i0 + 0 < N) rowstart[i0 + 0] = excl;
    if (i0 + 1 < N) rowstart[i0 + 1] = excl + v0;
    if (i0 + 2 < N) rowstart[i0 + 2] = excl + v0 + v1;
    if (i0 + 3 < N) rowstart[i0 + 3] = excl + v0 + v1 + v2;
    if (t == 255) partials[b] = woff + inc;
}

// phase 2: exclusive scan of partials (nb <= 64) in one wave
__global__ void scan_partials(int* __restrict__ partials, int nb) {
    int lane = threadIdx.x;
    int v = (lane < nb) ? partials[lane] : 0;
    int inc = v;
#pragma unroll
    for (int off = 1; off < 64; off <<= 1) {
        int u = __shfl_up(inc, off);
        if (lane >= off) inc += u;
    }
    if (lane < nb) partials[lane] = inc - v;
}

// phase 3: add block offsets
__global__ void scan_add(int* __restrict__ rowstart, const int* __restrict__ partials, int N) {
    int i = blockIdx.x * 256 + threadIdx.x;
    if (i < N) rowstart[i] += partials[i >> 10];
}

// ---------------------------------------------------------------------------
// CSR placement: cinfo[slot] = {dst, src, etype, orig_edge}
__global__ void place_edges(const int* __restrict__ ei, const int* __restrict__ etype,
                            int* __restrict__ cursor, const int* __restrict__ rowstart,
                            int4* __restrict__ cinfo, int E) {
    int e = blockIdx.x * 256 + threadIdx.x;
    if (e >= E) return;
    int s = ei[e], d = ei[E + e];
    int slot = rowstart[s] + atomicAdd(&cursor[s], 1);
    cinfo[slot] = make_int4(d, s, etype[e], e);
}

// ---------------------------------------------------------------------------
// Fused node phase (permuted columns -> vector stores). Reads z fragments once.
__global__ __launch_bounds__(256) void node_all(
        const float* __restrict__ z, const bf16x8* __restrict__ Ba,
        const bf16x8* __restrict__ Bb, const bf16x8* __restrict__ Bm1,
        const bf16x8* __restrict__ Bm2, const float* __restrict__ mb1,
        const float* __restrict__ mb2, unsigned short* __restrict__ Pa,
        unsigned short* __restrict__ Pb, unsigned short* __restrict__ zb16,
        float* __restrict__ Mx, int M) {
    __shared__ unsigned short Hs[64][136];
    const int l = threadIdx.x & 63;
    const int wv = threadIdx.x >> 6;
    const int c = l & 15, g = l >> 4;
    const int row = blockIdx.x * 64 + wv * 16 + c;
    const int rowc = row < M ? row : M - 1;
    const float* af = z + (size_t)rowc * 128 + g * 8;

    f32x4 acca[8], accb[8], acch[8];
#pragma unroll
    for (int ct = 0; ct < 8; ++ct)
#pragma unroll
        for (int r = 0; r < 4; ++r) { acca[ct][r] = 0.f; accb[ct][r] = 0.f; acch[ct][r] = 0.f; }

    bf16x8 afrag[4];
#pragma unroll
    for (int ks = 0; ks < 4; ++ks) {
        float4 x0 = *(const float4*)(af + ks * 32);
        float4 x1 = *(const float4*)(af + ks * 32 + 4);
        bf16x8 a;
        a[0] = bf16_rne(x0.x); a[1] = bf16_rne(x0.y);
        a[2] = bf16_rne(x0.z); a[3] = bf16_rne(x0.w);
        a[4] = bf16_rne(x1.x); a[5] = bf16_rne(x1.y);
        a[6] = bf16_rne(x1.z); a[7] = bf16_rne(x1.w);
        afrag[ks] = a;
        if (row < M)
            *(ushort8*)(zb16 + (size_t)row * 128 + ks * 32 + g * 8) = (ushort8)a;
    }
#pragma unroll
    for (int ks = 0; ks < 4; ++ks) {
#pragma unroll
        for (int ct = 0; ct < 8; ++ct) {
            acca[ct] = __builtin_amdgcn_mfma_f32_16x16x32_bf16(
                afrag[ks], Ba[(ks * 8 + ct) * 64 + l], acca[ct], 0, 0, 0);
            accb[ct] = __builtin_amdgcn_mfma_f32_16x16x32_bf16(
                afrag[ks], Bb[(ks * 8 + ct) * 64 + l], accb[ct], 0, 0, 0);
            acch[ct] = __builtin_amdgcn_mfma_f32_16x16x32_bf16(
                afrag[ks], Bm1[(ks * 8 + ct) * 64 + l], acch[ct], 0, 0, 0);
        }
    }

    // thread owns original columns c*8..c*8+7 -> vector stores
    float4 m10 = *(const float4*)(mb1 + c * 8);
    float4 m11 = *(const float4*)(mb1 + c * 8 + 4);
    float m1v[8] = {m10.x, m10.y, m10.z, m10.w, m11.x, m11.y, m11.z, m11.w};
#pragma unroll
    for (int r = 0; r < 4; ++r) {
        int rr = blockIdx.x * 64 + wv * 16 + g * 4 + r;
        bool ok = rr < M;
        ushort8 pa8, pb8, h8;
#pragma unroll
        for (int ct = 0; ct < 8; ++ct) {
            pa8[ct] = (unsigned short)bf16_rne(acca[ct][r]);
            pb8[ct] = (unsigned short)bf16_rne(accb[ct][r]);
            h8[ct] = (unsigned short)bf16_rne(fmaxf(acch[ct][r] + m1v[ct], 0.f));
        }
        if (ok) {
            *(ushort8*)(Pa + (size_t)rr * 128 + c * 8) = pa8;
            *(ushort8*)(Pb + (size_t)rr * 128 + c * 8) = pb8;
        }
        *(ushort8*)&Hs[wv * 16 + g * 4 + r][c * 8] = h8;
    }
    __syncthreads();

    // Mx = H@mw2 + mb2  (A-frags from canonical LDS rows)
    f32x4 accm[8];
#pragma unroll
    for (int ct = 0; ct < 8; ++ct)
#pragma unroll
        for (int r = 0; r < 4; ++r) accm[ct][r] = 0.f;
#pragma unroll
    for (int ks = 0; ks < 4; ++ks) {
        bf16x8 a = (bf16x8)(*(const ushort8*)&Hs[wv * 16 + c][ks * 32 + g * 8]);
#pragma unroll
        for (int ct = 0; ct < 8; ++ct)
            accm[ct] = __builtin_amdgcn_mfma_f32_16x16x32_bf16(
                a, Bm2[(ks * 8 + ct) * 64 + l], accm[ct], 0, 0, 0);
    }
    float4 m20 = *(const float4*)(mb2 + c * 8);
    float4 m21 = *(const float4*)(mb2 + c * 8 + 4);
#pragma unroll
    for (int r = 0; r < 4; ++r) {
        int rr = blockIdx.x * 64 + wv * 16 + g * 4 + r;
        if (rr >= M) continue;
        float4 o0 = make_float4(accm[0][r] + m20.x, accm[1][r] + m20.y,
                                accm[2][r] + m20.z, accm[3][r] + m20.w);
        float4 o1 = make_float4(accm[4][r] + m21.x, accm[5][r] + m21.y,
                                accm[6][r] + m21.z, accm[7][r] + m21.w);
        *(float4*)(Mx + (size_t)rr * 128 + c * 8) = o0;
        *(float4*)(Mx + (size_t)rr * 128 + c * 8 + 4) = o1;
    }
}

// ---------------------------------------------------------------------------
// MFMA edge kernel (CSR slot order, no LDS, no barriers).
// Permuted columns -> Pa/Pb row gathers are single 16B loads.
__global__ __launch_bounds__(256) void edge_mlp_mfma(
        const unsigned short* __restrict__ zb16, const int4* __restrict__ cinfo,
        const bf16x8* __restrict__ Bfr,
        const float* __restrict__ ew2, const float* __restrict__ eb2,
        const unsigned short* __restrict__ Pa, const unsigned short* __restrict__ Pb,
        const float* __restrict__ T2, float* __restrict__ expw,
        float* __restrict__ ssum, int E) {
    const int l = threadIdx.x & 63;
    const int wv = threadIdx.x >> 6;       // wave 0..3
    const int c = l & 15, g = l >> 4;      // frag coords
    const int slot0 = blockIdx.x * 64;

    const int ra = slot0 + wv * 16 + c;
    const int4 ciA = cinfo[ra];            // {dst, src, et, perm}
    const unsigned short* zi = zb16 + (size_t)ciA.y * 128 + g * 8;
    const unsigned short* zj = zb16 + (size_t)ciA.x * 128 + g * 8;

    f32x4 acc[8];
#pragma unroll
    for (int ct = 0; ct < 8; ++ct)
#pragma unroll
        for (int r = 0; r < 4; ++r) acc[ct][r] = 0.f;

#pragma unroll
    for (int ks = 0; ks < 4; ++ks) {
        ushort8 ui = *(const ushort8*)(zi + ks * 32);
        ushort8 uj = *(const ushort8*)(zj + ks * 32);
        bf16x8 a;
#pragma unroll
        for (int k = 0; k < 8; ++k)
            a[k] = bf16_rne(fabsf(bf16_to_f(ui[k]) - bf16_to_f(uj[k])));
#pragma unroll
        for (int ct = 0; ct < 8; ++ct) {
            bf16x8 b = Bfr[(ks * 8 + ct) * 64 + l];
            acc[ct] = __builtin_amdgcn_mfma_f32_16x16x32_bf16(a, b, acc[ct], 0, 0, 0);
        }
    }

    // ---- epilogue: thread owns original columns c*8..c*8+7 of rows eb+r ----
    const int eb = slot0 + wv * 16 + g * 4;
    int4 cr[4];
#pragma unroll
    for (int r = 0; r < 4; ++r) cr[r] = cinfo[eb + r];

    float4 w20 = *(const float4*)(ew2 + c * 8);
    float4 w21 = *(const float4*)(ew2 + c * 8 + 4);
    float w2v[8] = {w20.x, w20.y, w20.z, w20.w, w21.x, w21.y, w21.z, w21.w};

    float s[4] = {0.f, 0.f, 0.f, 0.f};
#pragma unroll
    for (int r = 0; r < 4; ++r) {
        ushort8 pa8 = *(const ushort8*)(Pa + (size_t)cr[r].y * 128 + c * 8);
        ushort8 pb8 = *(const ushort8*)(Pb + (size_t)cr[r].x * 128 + c * 8);
        const float* t2r = T2 + cr[r].z * 128 + c * 8;
        float4 t20 = *(const float4*)t2r;
        float4 t21 = *(const float4*)(t2r + 4);
        float t2v[8] = {t20.x, t20.y, t20.z, t20.w, t21.x, t21.y, t21.z, t21.w};
#pragma unroll
        for (int ct = 0; ct < 8; ++ct) {
            float h = acc[ct][r] + bf16_to_f(pa8[ct]) + bf16_to_f(pb8[ct]) + t2v[ct];
            s[r] = fmaf(fmaxf(h, 0.f), w2v[ct], s[r]);
        }
    }
#pragma unroll
    for (int r = 0; r < 4; ++r) {
        s[r] += __shfl_xor(s[r], 1);
        s[r] += __shfl_xor(s[r], 2);
        s[r] += __shfl_xor(s[r], 4);
        s[r] += __shfl_xor(s[r], 8);
    }
    if (c == 0) {
        const float eb2v = eb2[0];
#pragma unroll
        for (int r = 0; r < 4; ++r) {
            float w = 1.f / (1.f + expf(-(s[r] + eb2v)));
            float ewv = expf(w);
            expw[cr[r].w] = ewv;            // original edge order
            atomicAdd(&ssum[cr[r].y], ewv);
        }
    }
}

// ---------------------------------------------------------------------------
__global__ void alpha_k(const float* __restrict__ expw, const int* __restrict__ ei,
                        const float* __restrict__ ssum, float* __restrict__ oa, int E) {
    int e = blockIdx.x * 256 + threadIdx.x;
    if (e >= E) return;
    oa[e] = expw[e] / (ssum[ei[e]] + 1e-12f);
}

// ---------------------------------------------------------------------------
// Fused CSR gather + LayerNorm. One wave per node; float2 lanes; 2-edge unroll.
__global__ __launch_bounds__(256) void gather_ln(
        const float* __restrict__ z, const float* __restrict__ Mx,
        const int* __restrict__ rowstart, const int* __restrict__ deg,
        const int4* __restrict__ cinfo, const float* __restrict__ gamma,
        const float* __restrict__ beta, float* __restrict__ out, int N) {
    int wid = threadIdx.x >> 6, lane = threadIdx.x & 63;
    int n = blockIdx.x * 4 + wid;
    if (n >= N) return;
    int r0 = rowstart[n], dg = deg[n];
    float2 a0 = make_float2(0.f, 0.f), a1 = make_float2(0.f, 0.f);
    for (int c = 0; c < dg; c += 64) {
        int cnt = min(64, dg - c);
        int myd = (lane < cnt) ? cinfo[r0 + c + lane].x : 0;
        int j = 0;
        for (; j + 1 < cnt; j += 2) {
            int d0 = __shfl(myd, j), d1 = __shfl(myd, j + 1);
            float2 v0 = ((const float2*)(Mx + (size_t)d0 * 128))[lane];
            float2 v1 = ((const float2*)(Mx + (size_t)d1 * 128))[lane];
            a0.x += v0.x; a0.y += v0.y;
            a1.x += v1.x; a1.y += v1.y;
        }
        if (j < cnt) {
            int d0 = __shfl(myd, j);
            float2 v0 = ((const float2*)(Mx + (size_t)d0 * 128))[lane];
            a0.x += v0.x; a0.y += v0.y;
        }
    }
    float inv = 1.f / ((float)dg + 1e-12f);
    size_t base = (size_t)n * 128;
    float2 zz = ((const float2*)(z + base))[lane];
    float x0 = zz.x + (a0.x + a1.x) * inv;
    float x1 = zz.y + (a0.y + a1.y) * inv;
    float s = x0 + x1;
#pragma unroll
    for (int off = 1; off < 64; off <<= 1) s += __shfl_xor(s, off);
    float mu = s * (1.f / 128.f);
    float d0 = x0 - mu, d1 = x1 - mu;
    float v = d0 * d0 + d1 * d1;
#pragma unroll
    for (int off = 1; off < 64; off <<= 1) v += __shfl_xor(v, off);
    float rs = rsqrtf(v * (1.f / 128.f) + 1e-5f);
    float2 gg = ((const float2*)gamma)[lane];
    float2 bb = ((const float2*)beta)[lane];
    float2 o = make_float2(d0 * rs * gg.x + bb.x, d1 * rs * gg.y + bb.y);
    ((float2*)(out + base))[lane] = o;
}

// ---------------------------------------------------------------------------
extern "C" void kernel_launch(void* const* d_in, const int* in_sizes, int n_in,
                              void* d_out, int out_size, void* d_ws, size_t ws_size,
                              hipStream_t stream) {
    const float* z     = (const float*)d_in[0];
    const int*   ei    = (const int*)d_in[1];
    const int*   et    = (const int*)d_in[2];
    const float* temb  = (const float*)d_in[3];
    const float* ew1   = (const float*)d_in[4];
    const float* eb1   = (const float*)d_in[5];
    const float* ew2   = (const float*)d_in[6];
    const float* eb2   = (const float*)d_in[7];
    const float* mw1   = (const float*)d_in[8];
    const float* mb1   = (const float*)d_in[9];
    const float* mw2   = (const float*)d_in[10];
    const float* mb2   = (const float*)d_in[11];
    const float* gamma = (const float*)d_in[12];
    const float* beta  = (const float*)d_in[13];

    const int N = in_sizes[0] / 128;
    const int E = in_sizes[2];

    char* ws = (char*)d_ws;
    size_t off = 0;
    auto take = [&](size_t b) { char* p = ws + off; off += (b + 255) & ~(size_t)255; return p; };
    unsigned short* Pa    = (unsigned short*)take((size_t)N * 128 * 2);
    unsigned short* Pb    = (unsigned short*)take((size_t)N * 128 * 2);
    unsigned short* zb16  = (unsigned short*)take((size_t)N * 128 * 2);
    float*          Mx    = (float*)take((size_t)N * 128 * 4);
    char*           z0    = ws + off;               // contiguous zero region
    float*          ssum  = (float*)take((size_t)N * 4);
    int*            deg   = (int*)take((size_t)N * 4);
    int*            cursor= (int*)take((size_t)N * 4);
    size_t          zb    = (size_t)((ws + off) - z0);
    int*            rowst = (int*)take((size_t)N * 4);
    int*            parts = (int*)take(256 * 4);
    int4*           cinfo = (int4*)take((size_t)E * 16);
    float*          expw  = (float*)take((size_t)E * 4);
    float*          T2    = (float*)take(2 * 128 * 4);
    unsigned short* Wap   = (unsigned short*)take(2048 * 8 * 2);
    unsigned short* Wbp   = (unsigned short*)take(2048 * 8 * 2);
    unsigned short* Wcp   = (unsigned short*)take(2048 * 8 * 2);
    unsigned short* Mw1p  = (unsigned short*)take(2048 * 8 * 2);
    unsigned short* Mw2p  = (unsigned short*)take(2048 * 8 * 2);

    float* out_x = (float*)d_out;
    float* out_a = out_x + (size_t)N * 128;

    hipMemsetAsync(z0, 0, zb, stream);
    prep_all<<<6, 256, 0, stream>>>(temb, ew1, eb1, mw1, mw2,
                                    T2, Wap, Wbp, Wcp, Mw1p, Mw2p);

    // CSR build (parallel scan)
    const int nb = (N + 1023) / 1024;     // 49 <= 64
    deg_count<<<(E + 255) / 256, 256, 0, stream>>>(ei, deg, E);
    scan_local<<<nb, 256, 0, stream>>>(deg, rowst, parts, N);
    scan_partials<<<1, 64, 0, stream>>>(parts, nb);
    scan_add<<<(N + 255) / 256, 256, 0, stream>>>(rowst, parts, N);
    place_edges<<<(E + 255) / 256, 256, 0, stream>>>(ei, et, cursor, rowst, cinfo, E);

    // fused node phase (z read once)
    int gb = (N + 63) / 64;
    node_all<<<gb, 256, 0, stream>>>(z, (const bf16x8*)Wap, (const bf16x8*)Wbp,
                                     (const bf16x8*)Mw1p, (const bf16x8*)Mw2p,
                                     mb1, mb2, Pa, Pb, zb16, Mx, N);

    // edge branch (bf16 MFMA, CSR order, vectorized gathers)
    edge_mlp_mfma<<<E / 64, 256, 0, stream>>>(zb16, cinfo, (const bf16x8*)Wcp, ew2, eb2,
                                              Pa, Pb, T2, expw, ssum, E);
    alpha_k<<<(E + 255) / 256, 256, 0, stream>>>(expw, ei, ssum, out_a, E);
    gather_ln<<<(N + 3) / 4, 256, 0, stream>>>(z, Mx, rowst, deg, cinfo, gamma, beta, out_x, N);
}